// Round 10
// baseline (1138.190 us; speedup 1.0000x reference)
//
#include <hip/hip_runtime.h>
#include <hip/hip_bf16.h>
#include <stdint.h>

typedef __attribute__((ext_vector_type(8))) short bf16x8;
typedef __attribute__((ext_vector_type(4))) float f32x4;

// ALL-REGISTER design: intermediates never touch LDS. Every second GEMM is
// computed transposed (Y^T = W^T X^T) so each MFMA's D-registers are directly
// the next MFMA's A/B-fragment. Contraction-index mapping (k = 8*fg+j <->
// logical c = 16*(2m+u)+4*fg+(j&3), u=j>>2) is applied consistently to the
// register tiles AND the weight pre-pack, so operands always agree.
//
// x ownership: lane (fr=lane&15, fg=lane>>4) owns row fr, cols 16*nt+4*fg+r
// (nt,r in 0..3). Global I/O: f32x4 per nt -> 64 lanes cover 16 full 64-B
// sectors per instruction (fully coalesced).
//
// Occupancy/regalloc (round-9 lesson): 100 KB LDS pins 1 WG/CU = 12 waves =
// 3 waves/SIMD. amdgpu_waves_per_eu(3,3) pins the allocator to that target
// (VGPR budget 512/3 ~ 170) so it does NOT voluntarily spill to chase 6/SIMD
// (which LDS makes unreachable anyway). Round 9's 84-VGPR/2.1-GB-scratch
// failure was exactly that heuristic.
//
// LDS map (read-only after preload; NO in-loop hazards, NO barriers/fences):
//   [0, 98304)  96 weight fragments, bf16, frag f at byte f*1024 + lane*16:
//     f 0..23: QKV  (f = sel*8 + hd*2 + m)  A-frags of Wq^T/Wk^T, B-frags of Wv
//     f 24..31: Wp^T (f = 24 + nt*2 + m)
//     f 32..63: W1^T (f = 32 + t*2 + m)
//     f 64..95: W2^T (f = 64 + nt*8 + m)
//   [98304, 100864) params f32: g1@0 be1@64 g2@128 be2@192 bp@256 b2@320 b1@384

static __device__ __forceinline__ unsigned short f2bf(float f) {
    union { __hip_bfloat16 h; unsigned short u; } cv;
    cv.h = __float2bfloat16(f);
    return cv.u;
}
static __device__ __forceinline__ unsigned int f2bf2(float a, float b) {
    return (unsigned int)f2bf(a) | ((unsigned int)f2bf(b) << 16);
}
static __device__ __forceinline__ bf16x8 mk8(uint2 a, uint2 b) {
    union { uint4 u; bf16x8 v; } c;
    c.u = make_uint4(a.x, a.y, b.x, b.y);
    return c.v;
}

__global__ __attribute__((amdgpu_flat_work_group_size(768, 768),
                          amdgpu_waves_per_eu(3, 3)))
void fused_block(const float* __restrict__ xg,
                 const float* __restrict__ Wq, const float* __restrict__ Wk,
                 const float* __restrict__ Wv, const float* __restrict__ Wp,
                 const float* __restrict__ bp, const float* __restrict__ W1,
                 const float* __restrict__ b1, const float* __restrict__ W2,
                 const float* __restrict__ b2, const float* __restrict__ g1,
                 const float* __restrict__ be1, const float* __restrict__ g2,
                 const float* __restrict__ be2, float* __restrict__ out,
                 int nPairsTotal)
{
    __shared__ __align__(16) unsigned char LDS[100864];

    const int tid  = threadIdx.x;
    const int lane = tid & 63;
    const int wid  = tid >> 6;        // 0..11
    const int fr   = lane & 15;
    const int fg   = lane >> 4;

    // ---------------- weight pre-pack (bf16 fragments, pi-ordered) ----------
    {
        unsigned short* lw = (unsigned short*)LDS;
        #pragma unroll 1
        for (int e = tid; e < 49152; e += 768) {
            int j = e & 7, ln = (e >> 3) & 63, f = e >> 9;
            int fr_ = ln & 15, fg_ = ln >> 4;
            int u = j >> 2, r_ = j & 3;
            float src;
            if (f < 24) {                 // QKV: f = sel*8 + hd*2 + m
                int sel = f >> 3, hd = (f >> 1) & 3, m = f & 1;
                int c = 16*(2*m + u) + 4*fg_ + r_;
                const float* W = (sel == 0) ? Wq : ((sel == 1) ? Wk : Wv);
                src = W[hd*1024 + c*16 + fr_];
            } else if (f < 32) {          // Wp^T: f = 24 + nt*2 + m
                int t = f - 24, nt = t >> 1, m = t & 1;
                int d = 16*(2*m + u) + 4*fg_ + r_;
                src = Wp[d*64 + 16*nt + fr_];
            } else if (f < 64) {          // W1^T: f = 32 + t*2 + m
                int t = f - 32, tt = t >> 1, m = t & 1;
                int c = 16*(2*m + u) + 4*fg_ + r_;
                src = W1[c*256 + 16*tt + fr_];
            } else {                      // W2^T: f = 64 + nt*8 + m
                int t = f - 64, nt = t >> 3, m = t & 7;
                int n1 = 16*(2*m + u) + 4*fg_ + r_;
                src = W2[n1*64 + 16*nt + fr_];
            }
            lw[e] = f2bf(src);
        }
    }
    if (tid < 640) {   // params
        float v;
        if      (tid < 64)  v = g1[tid];
        else if (tid < 128) v = be1[tid - 64];
        else if (tid < 192) v = g2[tid - 128];
        else if (tid < 256) v = be2[tid - 192];
        else if (tid < 320) v = bp[tid - 256];
        else if (tid < 384) v = b2[tid - 320];
        else                v = b1[tid - 384];
        ((float*)(LDS + 98304))[tid] = v;
    }
    __syncthreads();

    const float* PG = (const float*)(LDS + 98304);
    #define WF(F)  (*(const bf16x8*)(LDS + ((F) << 10) + (lane << 4)))
    #define PG4(I) (*(const f32x4*)(PG + (I)))

    const int pipe = blockIdx.x * 12 + wid;   // 256*12 = 3072 pipes
    const f32x4 zf = {0.f, 0.f, 0.f, 0.f};
    const uint2 z2 = make_uint2(0u, 0u);
    const int xoff = fr*64 + 4*fg;            // float offset of (nt=0, r=0)

    // prologue: first tile
    f32x4 xn[4];
    if (pipe < nPairsTotal) {
        const float* xb0 = xg + (size_t)pipe * 1024;
        #pragma unroll
        for (int nt = 0; nt < 4; ++nt)
            xn[nt] = *(const f32x4*)(xb0 + xoff + 16*nt);
    }

    #pragma unroll 1
    for (int gp = pipe; gp < nPairsTotal; gp += 3072) {
        float* ob = out + (size_t)gp * 1024;

        f32x4 xv[4];
        #pragma unroll
        for (int nt = 0; nt < 4; ++nt) xv[nt] = xn[nt];

        {   // next-tile prefetch, in flight across the iteration
            int gpn = gp + 3072;
            if (gpn < nPairsTotal) {
                const float* xbn = xg + (size_t)gpn * 1024;
                #pragma unroll
                for (int nt = 0; nt < 4; ++nt)
                    xn[nt] = *(const f32x4*)(xbn + xoff + 16*nt);
            }
        }

        // ---- LN1 (row = fr; reduce across fg via xor 16,32) -> h frags ----
        bf16x8 hf0, hf1;
        {
            float s = 0.f, ss = 0.f;
            #pragma unroll
            for (int nt = 0; nt < 4; ++nt)
                #pragma unroll
                for (int r = 0; r < 4; ++r) { float v = xv[nt][r]; s += v; ss += v*v; }
            s += __shfl_xor(s, 16, 64); ss += __shfl_xor(ss, 16, 64);
            s += __shfl_xor(s, 32, 64); ss += __shfl_xor(ss, 32, 64);
            float mu  = s * 0.015625f;
            float inv = rsqrtf(ss * 0.015625f - mu*mu + 1e-5f);
            uint2 hw[2];
            #pragma unroll
            for (int m = 0; m < 2; ++m) {
                #pragma unroll
                for (int u = 0; u < 2; ++u) {
                    int nt = 2*m + u;
                    f32x4 gv = PG4(0  + 16*nt + 4*fg);
                    f32x4 bv = PG4(64 + 16*nt + 4*fg);
                    float y0 = (xv[nt][0]-mu)*inv*gv[0] + bv[0];
                    float y1 = (xv[nt][1]-mu)*inv*gv[1] + bv[1];
                    float y2 = (xv[nt][2]-mu)*inv*gv[2] + bv[2];
                    float y3 = (xv[nt][3]-mu)*inv*gv[3] + bv[3];
                    hw[u] = make_uint2(f2bf2(y0,y1), f2bf2(y2,y3));
                }
                if (m == 0) hf0 = mk8(hw[0], hw[1]); else hf1 = mk8(hw[0], hw[1]);
            }
        }

        // ---- QKV (Q^T,K^T transposed; V normal) -> per-lane bf16 tiles ----
        uint2 qb[4], kb[4], vb[4];
        #pragma unroll
        for (int hd = 0; hd < 4; ++hd) {
            f32x4 qa = __builtin_amdgcn_mfma_f32_16x16x32_bf16(WF(hd*2+0),  hf0, zf, 0,0,0);
            qa       = __builtin_amdgcn_mfma_f32_16x16x32_bf16(WF(hd*2+1),  hf1, qa, 0,0,0);
            qb[hd] = make_uint2(f2bf2(qa[0],qa[1]), f2bf2(qa[2],qa[3]));
            f32x4 ka = __builtin_amdgcn_mfma_f32_16x16x32_bf16(WF(8+hd*2+0), hf0, zf, 0,0,0);
            ka       = __builtin_amdgcn_mfma_f32_16x16x32_bf16(WF(8+hd*2+1), hf1, ka, 0,0,0);
            kb[hd] = make_uint2(f2bf2(ka[0],ka[1]), f2bf2(ka[2],ka[3]));
            f32x4 va = __builtin_amdgcn_mfma_f32_16x16x32_bf16(hf0, WF(16+hd*2+0), zf, 0,0,0);
            va       = __builtin_amdgcn_mfma_f32_16x16x32_bf16(hf1, WF(16+hd*2+1), va, 0,0,0);
            vb[hd] = make_uint2(f2bf2(va[0],va[1]), f2bf2(va[2],va[3]));
        }

        // ---- scores S^T = mfma(K,Q); softmax in-reg; O^T = mfma(V,P) ----
        // lane holds S[tq=fr][tk=4fg+r]; rowsum across fg via xor 16,32
        uint2 ob_[4];
        #pragma unroll
        for (int hd = 0; hd < 4; ++hd) {
            f32x4 sa_ = __builtin_amdgcn_mfma_f32_16x16x32_bf16(
                            mk8(kb[hd], z2), mk8(qb[hd], z2), zf, 0,0,0);
            float pw[4], rsum = 0.f;
            #pragma unroll
            for (int r = 0; r < 4; ++r) {
                int tk = 4*fg + r;
                bool valid = (((fr ^ tk) & 8) == 0) && ((tk & 7) <= (fr & 7));
                pw[r] = valid ? __expf(sa_[r] * 0.125f) : 0.f;   // scale = C^-0.5
                rsum += pw[r];
            }
            rsum += __shfl_xor(rsum, 16, 64);
            rsum += __shfl_xor(rsum, 32, 64);
            float pinv = __builtin_amdgcn_rcpf(rsum);
            uint2 pb = make_uint2(f2bf2(pw[0],pw[1]), f2bf2(pw[2],pw[3]));
            f32x4 oa = __builtin_amdgcn_mfma_f32_16x16x32_bf16(
                           mk8(vb[hd], z2), mk8(pb, z2), zf, 0,0,0);
            ob_[hd] = make_uint2(f2bf2(oa[0]*pinv, oa[1]*pinv),
                                 f2bf2(oa[2]*pinv, oa[3]*pinv));
        }

        // ---- proj: sa^T = Wp^T O^T (+bp), residual into xv ----
        #pragma unroll
        for (int nt = 0; nt < 4; ++nt) {
            f32x4 pa = __builtin_amdgcn_mfma_f32_16x16x32_bf16(
                           WF(24 + nt*2 + 0), mk8(ob_[0], ob_[1]), zf, 0,0,0);
            pa       = __builtin_amdgcn_mfma_f32_16x16x32_bf16(
                           WF(24 + nt*2 + 1), mk8(ob_[2], ob_[3]), pa, 0,0,0);
            f32x4 bv = PG4(256 + 16*nt + 4*fg);
            #pragma unroll
            for (int r = 0; r < 4; ++r) xv[nt][r] += pa[r] + bv[r];
        }

        // ---- LN2 -> h2 frags ----
        bf16x8 cf0, cf1;
        {
            float s = 0.f, ss = 0.f;
            #pragma unroll
            for (int nt = 0; nt < 4; ++nt)
                #pragma unroll
                for (int r = 0; r < 4; ++r) { float v = xv[nt][r]; s += v; ss += v*v; }
            s += __shfl_xor(s, 16, 64); ss += __shfl_xor(ss, 16, 64);
            s += __shfl_xor(s, 32, 64); ss += __shfl_xor(ss, 32, 64);
            float mu  = s * 0.015625f;
            float inv = rsqrtf(ss * 0.015625f - mu*mu + 1e-5f);
            uint2 hw[2];
            #pragma unroll
            for (int m = 0; m < 2; ++m) {
                #pragma unroll
                for (int u = 0; u < 2; ++u) {
                    int nt = 2*m + u;
                    f32x4 gv = PG4(128 + 16*nt + 4*fg);
                    f32x4 bv = PG4(192 + 16*nt + 4*fg);
                    float y0 = (xv[nt][0]-mu)*inv*gv[0] + bv[0];
                    float y1 = (xv[nt][1]-mu)*inv*gv[1] + bv[1];
                    float y2 = (xv[nt][2]-mu)*inv*gv[2] + bv[2];
                    float y3 = (xv[nt][3]-mu)*inv*gv[3] + bv[3];
                    hw[u] = make_uint2(f2bf2(y0,y1), f2bf2(y2,y3));
                }
                if (m == 0) cf0 = mk8(hw[0], hw[1]); else cf1 = mk8(hw[0], hw[1]);
            }
        }

        // ---- MLP: ff1^T = W1^T h2^T (relu,+b1) feeds ff2^T = W2^T ff1^T ----
        f32x4 ffa[4];
        #pragma unroll
        for (int nt = 0; nt < 4; ++nt) ffa[nt] = zf;
        #pragma unroll
        for (int m2 = 0; m2 < 8; ++m2) {
            uint2 fb[2];
            #pragma unroll
            for (int u = 0; u < 2; ++u) {
                int t = 2*m2 + u;
                f32x4 fa = __builtin_amdgcn_mfma_f32_16x16x32_bf16(
                               WF(32 + t*2 + 0), cf0, zf, 0,0,0);
                fa       = __builtin_amdgcn_mfma_f32_16x16x32_bf16(
                               WF(32 + t*2 + 1), cf1, fa, 0,0,0);
                f32x4 bv = PG4(384 + 16*t + 4*fg);
                fb[u] = make_uint2(
                    f2bf2(fmaxf(fa[0]+bv[0],0.f), fmaxf(fa[1]+bv[1],0.f)),
                    f2bf2(fmaxf(fa[2]+bv[2],0.f), fmaxf(fa[3]+bv[3],0.f)));
            }
            bf16x8 ffr = mk8(fb[0], fb[1]);
            #pragma unroll
            for (int nt = 0; nt < 4; ++nt)
                ffa[nt] = __builtin_amdgcn_mfma_f32_16x16x32_bf16(
                              WF(64 + nt*8 + m2), ffr, ffa[nt], 0,0,0);
        }

        // ---- +b2, residual 2, store ----
        #pragma unroll
        for (int nt = 0; nt < 4; ++nt) {
            f32x4 bv = PG4(320 + 16*nt + 4*fg);
            f32x4 o;
            #pragma unroll
            for (int r = 0; r < 4; ++r) o[r] = xv[nt][r] + ffa[nt][r] + bv[r];
            *(f32x4*)(ob + xoff + 16*nt) = o;
        }
    }
    #undef WF
    #undef PG4
}

extern "C" void kernel_launch(void* const* d_in, const int* in_sizes, int n_in,
                              void* d_out, int out_size, void* d_ws, size_t ws_size,
                              hipStream_t stream) {
    const float* x   = (const float*)d_in[0];
    const float* Wq  = (const float*)d_in[1];
    const float* Wk  = (const float*)d_in[2];
    const float* Wv  = (const float*)d_in[3];
    const float* Wp  = (const float*)d_in[4];
    const float* bp  = (const float*)d_in[5];
    const float* W1  = (const float*)d_in[6];
    const float* b1  = (const float*)d_in[7];
    const float* W2  = (const float*)d_in[8];
    const float* b2  = (const float*)d_in[9];
    const float* g1  = (const float*)d_in[10];
    const float* be1 = (const float*)d_in[11];
    const float* g2  = (const float*)d_in[12];
    const float* be2 = (const float*)d_in[13];
    int nPairs = in_sizes[0] / 1024;   // (B*T*C) / (2*8*64) = 32768
    fused_block<<<dim3(256), dim3(768), 0, stream>>>(
        x, Wq, Wk, Wv, Wp, bp, W1, b1, W2, b2, g1, be1, g2, be2,
        (float*)d_out, nPairs);
}

// Round 11
// 1111.374 us; speedup vs baseline: 1.0241x; 1.0241x over previous
//
#include <hip/hip_runtime.h>
#include <hip/hip_bf16.h>
#include <stdint.h>

typedef __attribute__((ext_vector_type(8))) short bf16x8;
typedef __attribute__((ext_vector_type(4))) float f32x4;

// ALL-REGISTER, FULLY-SCALARIZED design (round-10 lesson: aggregate arrays were
// demoted to scratch/localMem by promote-alloca -> 2.1 GB of scratch traffic;
// occupancy attributes can't fix that. Zero arrays = zero allocas = nothing
// demotable). Each wave processes TWO pairs (tiles A,B) so every weight
// fragment read from LDS feeds 2 MFMAs -> per-pair LDS traffic halved (DS pipe
// was the next bottleneck: ~77us/CU at 1 pair, ~43us at 2).
//
// Transposed-chaining math identical to round 9 (PASSED, absmax 0.031):
// k = 8*fg+j <-> logical c = 16*(2m+u)+4*fg+(j&3), u=j>>2, for register tiles
// and weight pre-pack alike. x ownership: lane(fr,fg) owns row fr, cols
// 16*nt+4*fg+r. Global I/O fully sector-coalesced (16x 64B sectors/instr).
//
// LDS map (read-only after preload; no in-loop stores, no barriers):
//   [0, 98304)  96 weight fragments, bf16, frag f at byte f*1024 + lane*16:
//     f 0..23: QKV (f = sel*8 + hd*2 + m)   f 24..31: Wp^T
//     f 32..63: W1^T (f = 32 + t*2 + m)     f 64..95: W2^T (f = 64 + nt*8 + m)
//   [98304, 100864) params f32: g1@0 be1@64 g2@128 be2@192 bp@256 b2@320 b1@384

static __device__ __forceinline__ unsigned short f2bf(float f) {
    union { __hip_bfloat16 h; unsigned short u; } cv;
    cv.h = __float2bfloat16(f);
    return cv.u;
}
static __device__ __forceinline__ unsigned int f2bf2(float a, float b) {
    return (unsigned int)f2bf(a) | ((unsigned int)f2bf(b) << 16);
}
static __device__ __forceinline__ bf16x8 mk8(uint2 a, uint2 b) {
    union { uint4 u; bf16x8 v; } c;
    c.u = make_uint4(a.x, a.y, b.x, b.y);
    return c.v;
}
static __device__ __forceinline__ uint2 packbf(f32x4 a) {
    return make_uint2(f2bf2(a[0], a[1]), f2bf2(a[2], a[3]));
}
static __device__ __forceinline__ uint2 lnq(f32x4 x, float mu, float inv, f32x4 g, f32x4 b) {
    return make_uint2(f2bf2((x[0]-mu)*inv*g[0]+b[0], (x[1]-mu)*inv*g[1]+b[1]),
                      f2bf2((x[2]-mu)*inv*g[2]+b[2], (x[3]-mu)*inv*g[3]+b[3]));
}
static __device__ __forceinline__ uint2 relupack(f32x4 a, f32x4 b) {
    return make_uint2(f2bf2(fmaxf(a[0]+b[0],0.f), fmaxf(a[1]+b[1],0.f)),
                      f2bf2(fmaxf(a[2]+b[2],0.f), fmaxf(a[3]+b[3],0.f)));
}

#define MFMA(A,B,C) __builtin_amdgcn_mfma_f32_16x16x32_bf16((A),(B),(C),0,0,0)
#define WFL(F) (*(const bf16x8*)(WB + ((F) << 10) + (lane << 4)))

// softmax (masked exp, no max-sub: |s|<~2 by construction) + PV for one tile
static __device__ __forceinline__ uint2 soft_pv(f32x4 sa, uint2 vw, int fr, int fg) {
    const f32x4 zf = {0.f,0.f,0.f,0.f};
    const uint2 z2 = make_uint2(0u,0u);
    int tk0 = 4*fg, frq = fr & 7;
    bool v8 = ((fr ^ tk0) & 8) == 0;
    float p0 = (v8 && (((tk0+0)&7) <= frq)) ? __expf(sa[0]*0.125f) : 0.f;
    float p1 = (v8 && (((tk0+1)&7) <= frq)) ? __expf(sa[1]*0.125f) : 0.f;
    float p2 = (v8 && (((tk0+2)&7) <= frq)) ? __expf(sa[2]*0.125f) : 0.f;
    float p3 = (v8 && (((tk0+3)&7) <= frq)) ? __expf(sa[3]*0.125f) : 0.f;
    float rsum = p0 + p1 + p2 + p3;
    rsum += __shfl_xor(rsum, 16, 64);
    rsum += __shfl_xor(rsum, 32, 64);
    float pinv = __builtin_amdgcn_rcpf(rsum);
    uint2 pb = make_uint2(f2bf2(p0,p1), f2bf2(p2,p3));
    f32x4 oa = MFMA(mk8(vw, z2), mk8(pb, z2), zf);
    return make_uint2(f2bf2(oa[0]*pinv, oa[1]*pinv), f2bf2(oa[2]*pinv, oa[3]*pinv));
}

// one head, both tiles: weight frags loaded ONCE, used 2x
static __device__ __forceinline__ void attn_head2(
    const unsigned char* WB, int lane, int fr, int fg,
    bf16x8 hA0, bf16x8 hA1, bf16x8 hB0, bf16x8 hB1, int hd,
    uint2& oA, uint2& oB)
{
    const f32x4 zf = {0.f,0.f,0.f,0.f};
    const uint2 z2 = make_uint2(0u,0u);
    bf16x8 wq0 = WFL(hd*2+0),    wq1 = WFL(hd*2+1);
    bf16x8 wk0 = WFL(8+hd*2+0),  wk1 = WFL(8+hd*2+1);
    bf16x8 wv0 = WFL(16+hd*2+0), wv1 = WFL(16+hd*2+1);
    {   // tile A
        f32x4 qa = MFMA(wq0, hA0, zf); qa = MFMA(wq1, hA1, qa);
        f32x4 ka = MFMA(wk0, hA0, zf); ka = MFMA(wk1, hA1, ka);
        f32x4 va = MFMA(hA0, wv0, zf); va = MFMA(hA1, wv1, va);
        uint2 qw = packbf(qa), kw = packbf(ka), vw = packbf(va);
        f32x4 sa = MFMA(mk8(kw, z2), mk8(qw, z2), zf);
        oA = soft_pv(sa, vw, fr, fg);
    }
    {   // tile B
        f32x4 qa = MFMA(wq0, hB0, zf); qa = MFMA(wq1, hB1, qa);
        f32x4 ka = MFMA(wk0, hB0, zf); ka = MFMA(wk1, hB1, ka);
        f32x4 va = MFMA(hB0, wv0, zf); va = MFMA(hB1, wv1, va);
        uint2 qw = packbf(qa), kw = packbf(ka), vw = packbf(va);
        f32x4 sa = MFMA(mk8(kw, z2), mk8(qw, z2), zf);
        oB = soft_pv(sa, vw, fr, fg);
    }
}

__global__ __attribute__((amdgpu_flat_work_group_size(1024, 1024),
                          amdgpu_waves_per_eu(3, 4)))
void fused_block(const float* __restrict__ xg,
                 const float* __restrict__ Wq, const float* __restrict__ Wk,
                 const float* __restrict__ Wv, const float* __restrict__ Wp,
                 const float* __restrict__ bp, const float* __restrict__ W1,
                 const float* __restrict__ b1, const float* __restrict__ W2,
                 const float* __restrict__ b2, const float* __restrict__ g1,
                 const float* __restrict__ be1, const float* __restrict__ g2,
                 const float* __restrict__ be2, float* __restrict__ out,
                 int nPairsTotal)
{
    __shared__ __align__(16) unsigned char LDS[100864];

    const int tid  = threadIdx.x;
    const int lane = tid & 63;
    const int wid  = tid >> 6;        // 0..15
    const int fr   = lane & 15;
    const int fg   = lane >> 4;

    // ---------------- weight pre-pack (identical to round 9) ----------------
    {
        unsigned short* lw = (unsigned short*)LDS;
        #pragma unroll 1
        for (int e = tid; e < 49152; e += 1024) {
            int j = e & 7, ln = (e >> 3) & 63, f = e >> 9;
            int fr_ = ln & 15, fg_ = ln >> 4;
            int u = j >> 2, r_ = j & 3;
            float src;
            if (f < 24) {                 // QKV: f = sel*8 + hd*2 + m
                int sel = f >> 3, hd = (f >> 1) & 3, m = f & 1;
                int c = 16*(2*m + u) + 4*fg_ + r_;
                const float* W = (sel == 0) ? Wq : ((sel == 1) ? Wk : Wv);
                src = W[hd*1024 + c*16 + fr_];
            } else if (f < 32) {          // Wp^T
                int t = f - 24, nt = t >> 1, m = t & 1;
                int d = 16*(2*m + u) + 4*fg_ + r_;
                src = Wp[d*64 + 16*nt + fr_];
            } else if (f < 64) {          // W1^T
                int t = f - 32, tt = t >> 1, m = t & 1;
                int c = 16*(2*m + u) + 4*fg_ + r_;
                src = W1[c*256 + 16*tt + fr_];
            } else {                      // W2^T
                int t = f - 64, nt = t >> 3, m = t & 7;
                int n1 = 16*(2*m + u) + 4*fg_ + r_;
                src = W2[n1*64 + 16*nt + fr_];
            }
            lw[e] = f2bf(src);
        }
    }
    if (tid < 640) {   // params
        float v;
        if      (tid < 64)  v = g1[tid];
        else if (tid < 128) v = be1[tid - 64];
        else if (tid < 192) v = g2[tid - 128];
        else if (tid < 256) v = be2[tid - 192];
        else if (tid < 320) v = bp[tid - 256];
        else if (tid < 384) v = b2[tid - 320];
        else                v = b1[tid - 384];
        ((float*)(LDS + 98304))[tid] = v;
    }
    __syncthreads();

    const unsigned char* WB = LDS;
    const float* PG = (const float*)(LDS + 98304);
    #define PG4(I) (*(const f32x4*)(PG + (I) + 4*fg))

    const int pipe = blockIdx.x * 16 + wid;   // 256*16 = 4096 pipes
    const f32x4 zf = {0.f, 0.f, 0.f, 0.f};
    const int xoff = fr*64 + 4*fg;
    const int nP2 = nPairsTotal >> 1;         // pair-pairs

    #pragma unroll 1
    for (int gp2 = pipe; gp2 < nP2; gp2 += 4096) {
        const float* xb = xg + (size_t)gp2 * 2048;
        float*      obp = out + (size_t)gp2 * 2048;

        f32x4 xA0 = *(const f32x4*)(xb + xoff);
        f32x4 xA1 = *(const f32x4*)(xb + xoff + 16);
        f32x4 xA2 = *(const f32x4*)(xb + xoff + 32);
        f32x4 xA3 = *(const f32x4*)(xb + xoff + 48);
        f32x4 xB0 = *(const f32x4*)(xb + 1024 + xoff);
        f32x4 xB1 = *(const f32x4*)(xb + 1024 + xoff + 16);
        f32x4 xB2 = *(const f32x4*)(xb + 1024 + xoff + 32);
        f32x4 xB3 = *(const f32x4*)(xb + 1024 + xoff + 48);

        #define ACC4(S,SS,V) { S += V[0]+V[1]+V[2]+V[3]; \
                               SS += V[0]*V[0]+V[1]*V[1]+V[2]*V[2]+V[3]*V[3]; }

        // ---- LN1 (shared params) -> h fragments for A and B ----
        bf16x8 hA0, hA1, hB0, hB1;
        {
            float sA=0.f, qA=0.f, sB=0.f, qB=0.f;
            ACC4(sA,qA,xA0); ACC4(sA,qA,xA1); ACC4(sA,qA,xA2); ACC4(sA,qA,xA3);
            ACC4(sB,qB,xB0); ACC4(sB,qB,xB1); ACC4(sB,qB,xB2); ACC4(sB,qB,xB3);
            sA += __shfl_xor(sA,16,64); qA += __shfl_xor(qA,16,64);
            sA += __shfl_xor(sA,32,64); qA += __shfl_xor(qA,32,64);
            sB += __shfl_xor(sB,16,64); qB += __shfl_xor(qB,16,64);
            sB += __shfl_xor(sB,32,64); qB += __shfl_xor(qB,32,64);
            float muA = sA*0.015625f, invA = rsqrtf(qA*0.015625f - muA*muA + 1e-5f);
            float muB = sB*0.015625f, invB = rsqrtf(qB*0.015625f - muB*muB + 1e-5f);
            f32x4 ga0 = PG4(0),  ga1 = PG4(16), ga2 = PG4(32), ga3 = PG4(48);
            f32x4 bb0 = PG4(64), bb1 = PG4(80), bb2 = PG4(96), bb3 = PG4(112);
            hA0 = mk8(lnq(xA0,muA,invA,ga0,bb0), lnq(xA1,muA,invA,ga1,bb1));
            hA1 = mk8(lnq(xA2,muA,invA,ga2,bb2), lnq(xA3,muA,invA,ga3,bb3));
            hB0 = mk8(lnq(xB0,muB,invB,ga0,bb0), lnq(xB1,muB,invB,ga1,bb1));
            hB1 = mk8(lnq(xB2,muB,invB,ga2,bb2), lnq(xB3,muB,invB,ga3,bb3));
        }

        // ---- attention: 4 heads, both tiles, weight frags shared ----
        uint2 oA0,oA1,oA2,oA3, oB0,oB1,oB2,oB3;
        attn_head2(WB, lane, fr, fg, hA0,hA1, hB0,hB1, 0, oA0, oB0);
        attn_head2(WB, lane, fr, fg, hA0,hA1, hB0,hB1, 1, oA1, oB1);
        attn_head2(WB, lane, fr, fg, hA0,hA1, hB0,hB1, 2, oA2, oB2);
        attn_head2(WB, lane, fr, fg, hA0,hA1, hB0,hB1, 3, oA3, oB3);

        // ---- proj + bp + residual 1 ----
        {
            bf16x8 oAlo = mk8(oA0,oA1), oAhi = mk8(oA2,oA3);
            bf16x8 oBlo = mk8(oB0,oB1), oBhi = mk8(oB2,oB3);
            #define PROJ(NT, XA, XB) { \
                bf16x8 wp0 = WFL(24+(NT)*2+0), wp1 = WFL(24+(NT)*2+1); \
                f32x4 pa = MFMA(wp0, oAlo, zf); pa = MFMA(wp1, oAhi, pa); \
                f32x4 pb = MFMA(wp0, oBlo, zf); pb = MFMA(wp1, oBhi, pb); \
                f32x4 bv = PG4(256 + 16*(NT)); \
                XA[0]+=pa[0]+bv[0]; XA[1]+=pa[1]+bv[1]; XA[2]+=pa[2]+bv[2]; XA[3]+=pa[3]+bv[3]; \
                XB[0]+=pb[0]+bv[0]; XB[1]+=pb[1]+bv[1]; XB[2]+=pb[2]+bv[2]; XB[3]+=pb[3]+bv[3]; }
            PROJ(0, xA0, xB0); PROJ(1, xA1, xB1); PROJ(2, xA2, xB2); PROJ(3, xA3, xB3);
            #undef PROJ
        }

        // ---- LN2 -> h2 fragments ----
        bf16x8 cA0, cA1, cB0, cB1;
        {
            float sA=0.f, qA=0.f, sB=0.f, qB=0.f;
            ACC4(sA,qA,xA0); ACC4(sA,qA,xA1); ACC4(sA,qA,xA2); ACC4(sA,qA,xA3);
            ACC4(sB,qB,xB0); ACC4(sB,qB,xB1); ACC4(sB,qB,xB2); ACC4(sB,qB,xB3);
            sA += __shfl_xor(sA,16,64); qA += __shfl_xor(qA,16,64);
            sA += __shfl_xor(sA,32,64); qA += __shfl_xor(qA,32,64);
            sB += __shfl_xor(sB,16,64); qB += __shfl_xor(qB,16,64);
            sB += __shfl_xor(sB,32,64); qB += __shfl_xor(qB,32,64);
            float muA = sA*0.015625f, invA = rsqrtf(qA*0.015625f - muA*muA + 1e-5f);
            float muB = sB*0.015625f, invB = rsqrtf(qB*0.015625f - muB*muB + 1e-5f);
            f32x4 ga0 = PG4(128), ga1 = PG4(144), ga2 = PG4(160), ga3 = PG4(176);
            f32x4 bb0 = PG4(192), bb1 = PG4(208), bb2 = PG4(224), bb3 = PG4(240);
            cA0 = mk8(lnq(xA0,muA,invA,ga0,bb0), lnq(xA1,muA,invA,ga1,bb1));
            cA1 = mk8(lnq(xA2,muA,invA,ga2,bb2), lnq(xA3,muA,invA,ga3,bb3));
            cB0 = mk8(lnq(xB0,muB,invB,ga0,bb0), lnq(xB1,muB,invB,ga1,bb1));
            cB1 = mk8(lnq(xB2,muB,invB,ga2,bb2), lnq(xB3,muB,invB,ga3,bb3));
        }

        // ---- MLP: W1/W2 frags shared across tiles ----
        f32x4 fA0=zf, fA1=zf, fA2=zf, fA3=zf, fB0=zf, fB1=zf, fB2=zf, fB3=zf;
        #pragma unroll
        for (int m2 = 0; m2 < 8; ++m2) {
            int t0 = 2*m2, t1 = 2*m2 + 1;
            bf16x8 w10 = WFL(32+t0*2+0), w11 = WFL(32+t0*2+1);
            f32x4 bi0 = PG4(384 + 16*t0);
            f32x4 aa = MFMA(w10, cA0, zf); aa = MFMA(w11, cA1, aa);
            f32x4 ab = MFMA(w10, cB0, zf); ab = MFMA(w11, cB1, ab);
            uint2 frA0 = relupack(aa, bi0), frB0 = relupack(ab, bi0);
            bf16x8 w12 = WFL(32+t1*2+0), w13 = WFL(32+t1*2+1);
            f32x4 bi1 = PG4(384 + 16*t1);
            f32x4 ac = MFMA(w12, cA0, zf); ac = MFMA(w13, cA1, ac);
            f32x4 ad = MFMA(w12, cB0, zf); ad = MFMA(w13, cB1, ad);
            uint2 frA1 = relupack(ac, bi1), frB1 = relupack(ad, bi1);
            bf16x8 ffrA = mk8(frA0, frA1), ffrB = mk8(frB0, frB1);
            bf16x8 w20 = WFL(64 + 0*8 + m2);
            fA0 = MFMA(w20, ffrA, fA0); fB0 = MFMA(w20, ffrB, fB0);
            bf16x8 w21 = WFL(64 + 1*8 + m2);
            fA1 = MFMA(w21, ffrA, fA1); fB1 = MFMA(w21, ffrB, fB1);
            bf16x8 w22 = WFL(64 + 2*8 + m2);
            fA2 = MFMA(w22, ffrA, fA2); fB2 = MFMA(w22, ffrB, fB2);
            bf16x8 w23 = WFL(64 + 3*8 + m2);
            fA3 = MFMA(w23, ffrA, fA3); fB3 = MFMA(w23, ffrB, fB3);
        }

        // ---- +b2, residual 2, store ----
        #define STORE(NT, XA, FA, XB, FB) { \
            f32x4 bv = PG4(320 + 16*(NT)); \
            f32x4 oa, obv; \
            oa[0]=XA[0]+FA[0]+bv[0]; oa[1]=XA[1]+FA[1]+bv[1]; \
            oa[2]=XA[2]+FA[2]+bv[2]; oa[3]=XA[3]+FA[3]+bv[3]; \
            obv[0]=XB[0]+FB[0]+bv[0]; obv[1]=XB[1]+FB[1]+bv[1]; \
            obv[2]=XB[2]+FB[2]+bv[2]; obv[3]=XB[3]+FB[3]+bv[3]; \
            *(f32x4*)(obp + xoff + 16*(NT)) = oa; \
            *(f32x4*)(obp + 1024 + xoff + 16*(NT)) = obv; }
        STORE(0, xA0, fA0, xB0, fB0); STORE(1, xA1, fA1, xB1, fB1);
        STORE(2, xA2, fA2, xB2, fB2); STORE(3, xA3, fA3, xB3, fB3);
        #undef STORE
        #undef ACC4
    }
    #undef PG4
}

extern "C" void kernel_launch(void* const* d_in, const int* in_sizes, int n_in,
                              void* d_out, int out_size, void* d_ws, size_t ws_size,
                              hipStream_t stream) {
    const float* x   = (const float*)d_in[0];
    const float* Wq  = (const float*)d_in[1];
    const float* Wk  = (const float*)d_in[2];
    const float* Wv  = (const float*)d_in[3];
    const float* Wp  = (const float*)d_in[4];
    const float* bp  = (const float*)d_in[5];
    const float* W1  = (const float*)d_in[6];
    const float* b1  = (const float*)d_in[7];
    const float* W2  = (const float*)d_in[8];
    const float* b2  = (const float*)d_in[9];
    const float* g1  = (const float*)d_in[10];
    const float* be1 = (const float*)d_in[11];
    const float* g2  = (const float*)d_in[12];
    const float* be2 = (const float*)d_in[13];
    int nPairs = in_sizes[0] / 1024;   // (B*T*C) / (2*8*64) = 32768
    fused_block<<<dim3(256), dim3(1024), 0, stream>>>(
        x, Wq, Wk, Wv, Wp, bp, W1, b1, W2, b2, g1, be1, g2, be2,
        (float*)d_out, nPairs);
}

// Round 12
// 843.656 us; speedup vs baseline: 1.3491x; 1.3173x over previous
//
#include <hip/hip_runtime.h>
#include <hip/hip_bf16.h>
#include <stdint.h>

typedef __attribute__((ext_vector_type(8))) short bf16x8;
typedef __attribute__((ext_vector_type(4))) float f32x4;

// ALL-REGISTER, FULLY-SCALARIZED transformer block; 2 pairs (tiles A,B) per
// wave so each LDS weight-fragment read feeds 2 MFMAs.
//
// REGALLOC REGIME (rounds 9-11 lesson): with 768/1024-thread workgroups the
// backend pins VGPRs to a high-occupancy budget (64-84) and spills the live
// set to scratch (~2-3 GB of TCC traffic, 8x slowdown). 512-thread blocks +
// __launch_bounds__(512,2) empirically yield a ~256-VGPR budget (rounds 2/4:
// VGPR 116-120, zero scratch). LDS (~98.5 KB) pins 1 WG/CU = 2 waves/SIMD
// anyway, so the (512,2) bound sacrifices nothing.
//
// Transposed-chaining math identical to rounds 9-11 (PASSED, absmax 0.031):
// k = 8*fg+j <-> logical c = 16*(2m+u)+4*fg+(j&3), u=j>>2, applied to both
// register tiles and the weight pre-pack. x ownership: lane(fr,fg) owns row
// fr, cols 16*nt+4*fg+r. Each f32x4 global access covers 16 full 64-B
// sectors -> fully coalesced.
//
// LDS map (read-only after preload; no in-loop stores, no barriers):
//   [0, 98304)  96 weight fragments, bf16, frag f at byte f*1024 + lane*16:
//     f 0..23: QKV (f = sel*8 + hd*2 + m)   f 24..31: Wp^T
//     f 32..63: W1^T (f = 32 + t*2 + m)     f 64..95: W2^T (f = 64 + nt*8 + m)
//   [98304, 100864) params f32: g1@0 be1@64 g2@128 be2@192 bp@256 b2@320 b1@384

static __device__ __forceinline__ unsigned short f2bf(float f) {
    union { __hip_bfloat16 h; unsigned short u; } cv;
    cv.h = __float2bfloat16(f);
    return cv.u;
}
static __device__ __forceinline__ unsigned int f2bf2(float a, float b) {
    return (unsigned int)f2bf(a) | ((unsigned int)f2bf(b) << 16);
}
static __device__ __forceinline__ bf16x8 mk8(uint2 a, uint2 b) {
    union { uint4 u; bf16x8 v; } c;
    c.u = make_uint4(a.x, a.y, b.x, b.y);
    return c.v;
}
static __device__ __forceinline__ uint2 packbf(f32x4 a) {
    return make_uint2(f2bf2(a[0], a[1]), f2bf2(a[2], a[3]));
}
static __device__ __forceinline__ uint2 lnq(f32x4 x, float mu, float inv, f32x4 g, f32x4 b) {
    return make_uint2(f2bf2((x[0]-mu)*inv*g[0]+b[0], (x[1]-mu)*inv*g[1]+b[1]),
                      f2bf2((x[2]-mu)*inv*g[2]+b[2], (x[3]-mu)*inv*g[3]+b[3]));
}
static __device__ __forceinline__ uint2 relupack(f32x4 a, f32x4 b) {
    return make_uint2(f2bf2(fmaxf(a[0]+b[0],0.f), fmaxf(a[1]+b[1],0.f)),
                      f2bf2(fmaxf(a[2]+b[2],0.f), fmaxf(a[3]+b[3],0.f)));
}

#define MFMA(A,B,C) __builtin_amdgcn_mfma_f32_16x16x32_bf16((A),(B),(C),0,0,0)
#define WFL(F) (*(const bf16x8*)(WB + ((F) << 10) + (lane << 4)))

// softmax (masked exp, no max-sub: |s|<~2 by construction) + PV for one tile
static __device__ __forceinline__ uint2 soft_pv(f32x4 sa, uint2 vw, int fr, int fg) {
    const f32x4 zf = {0.f,0.f,0.f,0.f};
    const uint2 z2 = make_uint2(0u,0u);
    int tk0 = 4*fg, frq = fr & 7;
    bool v8 = ((fr ^ tk0) & 8) == 0;
    float p0 = (v8 && (((tk0+0)&7) <= frq)) ? __expf(sa[0]*0.125f) : 0.f;
    float p1 = (v8 && (((tk0+1)&7) <= frq)) ? __expf(sa[1]*0.125f) : 0.f;
    float p2 = (v8 && (((tk0+2)&7) <= frq)) ? __expf(sa[2]*0.125f) : 0.f;
    float p3 = (v8 && (((tk0+3)&7) <= frq)) ? __expf(sa[3]*0.125f) : 0.f;
    float rsum = p0 + p1 + p2 + p3;
    rsum += __shfl_xor(rsum, 16, 64);
    rsum += __shfl_xor(rsum, 32, 64);
    float pinv = __builtin_amdgcn_rcpf(rsum);
    uint2 pb = make_uint2(f2bf2(p0,p1), f2bf2(p2,p3));
    f32x4 oa = MFMA(mk8(vw, z2), mk8(pb, z2), zf);
    return make_uint2(f2bf2(oa[0]*pinv, oa[1]*pinv), f2bf2(oa[2]*pinv, oa[3]*pinv));
}

// one head, both tiles: weight frags loaded ONCE, used 2x
static __device__ __forceinline__ void attn_head2(
    const unsigned char* WB, int lane, int fr, int fg,
    bf16x8 hA0, bf16x8 hA1, bf16x8 hB0, bf16x8 hB1, int hd,
    uint2& oA, uint2& oB)
{
    const f32x4 zf = {0.f,0.f,0.f,0.f};
    const uint2 z2 = make_uint2(0u,0u);
    bf16x8 wq0 = WFL(hd*2+0),    wq1 = WFL(hd*2+1);
    bf16x8 wk0 = WFL(8+hd*2+0),  wk1 = WFL(8+hd*2+1);
    bf16x8 wv0 = WFL(16+hd*2+0), wv1 = WFL(16+hd*2+1);
    {   // tile A
        f32x4 qa = MFMA(wq0, hA0, zf); qa = MFMA(wq1, hA1, qa);
        f32x4 ka = MFMA(wk0, hA0, zf); ka = MFMA(wk1, hA1, ka);
        f32x4 va = MFMA(hA0, wv0, zf); va = MFMA(hA1, wv1, va);
        uint2 qw = packbf(qa), kw = packbf(ka), vw = packbf(va);
        f32x4 sa = MFMA(mk8(kw, z2), mk8(qw, z2), zf);
        oA = soft_pv(sa, vw, fr, fg);
    }
    {   // tile B
        f32x4 qa = MFMA(wq0, hB0, zf); qa = MFMA(wq1, hB1, qa);
        f32x4 ka = MFMA(wk0, hB0, zf); ka = MFMA(wk1, hB1, ka);
        f32x4 va = MFMA(hB0, wv0, zf); va = MFMA(hB1, wv1, va);
        uint2 qw = packbf(qa), kw = packbf(ka), vw = packbf(va);
        f32x4 sa = MFMA(mk8(kw, z2), mk8(qw, z2), zf);
        oB = soft_pv(sa, vw, fr, fg);
    }
}

__global__ __launch_bounds__(512, 2)
void fused_block(const float* __restrict__ xg,
                 const float* __restrict__ Wq, const float* __restrict__ Wk,
                 const float* __restrict__ Wv, const float* __restrict__ Wp,
                 const float* __restrict__ bp, const float* __restrict__ W1,
                 const float* __restrict__ b1, const float* __restrict__ W2,
                 const float* __restrict__ b2, const float* __restrict__ g1,
                 const float* __restrict__ be1, const float* __restrict__ g2,
                 const float* __restrict__ be2, float* __restrict__ out,
                 int nPairsTotal)
{
    __shared__ __align__(16) unsigned char LDS[100864];

    const int tid  = threadIdx.x;
    const int lane = tid & 63;
    const int wid  = tid >> 6;        // 0..7
    const int fr   = lane & 15;
    const int fg   = lane >> 4;

    // ---------------- weight pre-pack (identical math to round 9) -----------
    {
        unsigned short* lw = (unsigned short*)LDS;
        #pragma unroll 1
        for (int e = tid; e < 49152; e += 512) {
            int j = e & 7, ln = (e >> 3) & 63, f = e >> 9;
            int fr_ = ln & 15, fg_ = ln >> 4;
            int u = j >> 2, r_ = j & 3;
            float src;
            if (f < 24) {                 // QKV: f = sel*8 + hd*2 + m
                int sel = f >> 3, hd = (f >> 1) & 3, m = f & 1;
                int c = 16*(2*m + u) + 4*fg_ + r_;
                const float* W = (sel == 0) ? Wq : ((sel == 1) ? Wk : Wv);
                src = W[hd*1024 + c*16 + fr_];
            } else if (f < 32) {          // Wp^T
                int t = f - 24, nt = t >> 1, m = t & 1;
                int d = 16*(2*m + u) + 4*fg_ + r_;
                src = Wp[d*64 + 16*nt + fr_];
            } else if (f < 64) {          // W1^T
                int t = f - 32, tt = t >> 1, m = t & 1;
                int c = 16*(2*m + u) + 4*fg_ + r_;
                src = W1[c*256 + 16*tt + fr_];
            } else {                      // W2^T
                int t = f - 64, nt = t >> 3, m = t & 7;
                int n1 = 16*(2*m + u) + 4*fg_ + r_;
                src = W2[n1*64 + 16*nt + fr_];
            }
            lw[e] = f2bf(src);
        }
    }
    #pragma unroll 1
    for (int t = tid; t < 640; t += 512) {   // params
        float v;
        if      (t < 64)  v = g1[t];
        else if (t < 128) v = be1[t - 64];
        else if (t < 192) v = g2[t - 128];
        else if (t < 256) v = be2[t - 192];
        else if (t < 320) v = bp[t - 256];
        else if (t < 384) v = b2[t - 320];
        else              v = b1[t - 384];
        ((float*)(LDS + 98304))[t] = v;
    }
    __syncthreads();

    const unsigned char* WB = LDS;
    const float* PG = (const float*)(LDS + 98304);
    #define PG4(I) (*(const f32x4*)(PG + (I) + 4*fg))

    const int pipe = blockIdx.x * 8 + wid;    // 256*8 = 2048 pipes
    const f32x4 zf = {0.f, 0.f, 0.f, 0.f};
    const int xoff = fr*64 + 4*fg;
    const int nP2 = nPairsTotal >> 1;         // pair-pairs (16384)

    // prologue: prefetch first tile pair
    f32x4 nA0, nA1, nA2, nA3, nB0, nB1, nB2, nB3;
    if (pipe < nP2) {
        const float* xb0 = xg + (size_t)pipe * 2048;
        nA0 = *(const f32x4*)(xb0 + xoff);
        nA1 = *(const f32x4*)(xb0 + xoff + 16);
        nA2 = *(const f32x4*)(xb0 + xoff + 32);
        nA3 = *(const f32x4*)(xb0 + xoff + 48);
        nB0 = *(const f32x4*)(xb0 + 1024 + xoff);
        nB1 = *(const f32x4*)(xb0 + 1024 + xoff + 16);
        nB2 = *(const f32x4*)(xb0 + 1024 + xoff + 32);
        nB3 = *(const f32x4*)(xb0 + 1024 + xoff + 48);
    }

    #pragma unroll 1
    for (int gp2 = pipe; gp2 < nP2; gp2 += 2048) {
        float* obp = out + (size_t)gp2 * 2048;

        f32x4 xA0 = nA0, xA1 = nA1, xA2 = nA2, xA3 = nA3;
        f32x4 xB0 = nB0, xB1 = nB1, xB2 = nB2, xB3 = nB3;

        {   // next-tile prefetch, in flight across the iteration
            int gpn = gp2 + 2048;
            if (gpn < nP2) {
                const float* xbn = xg + (size_t)gpn * 2048;
                nA0 = *(const f32x4*)(xbn + xoff);
                nA1 = *(const f32x4*)(xbn + xoff + 16);
                nA2 = *(const f32x4*)(xbn + xoff + 32);
                nA3 = *(const f32x4*)(xbn + xoff + 48);
                nB0 = *(const f32x4*)(xbn + 1024 + xoff);
                nB1 = *(const f32x4*)(xbn + 1024 + xoff + 16);
                nB2 = *(const f32x4*)(xbn + 1024 + xoff + 32);
                nB3 = *(const f32x4*)(xbn + 1024 + xoff + 48);
            }
        }

        #define ACC4(S,SS,V) { S += V[0]+V[1]+V[2]+V[3]; \
                               SS += V[0]*V[0]+V[1]*V[1]+V[2]*V[2]+V[3]*V[3]; }

        // ---- LN1 (shared params) -> h fragments for A and B ----
        bf16x8 hA0, hA1, hB0, hB1;
        {
            float sA=0.f, qA=0.f, sB=0.f, qB=0.f;
            ACC4(sA,qA,xA0); ACC4(sA,qA,xA1); ACC4(sA,qA,xA2); ACC4(sA,qA,xA3);
            ACC4(sB,qB,xB0); ACC4(sB,qB,xB1); ACC4(sB,qB,xB2); ACC4(sB,qB,xB3);
            sA += __shfl_xor(sA,16,64); qA += __shfl_xor(qA,16,64);
            sA += __shfl_xor(sA,32,64); qA += __shfl_xor(qA,32,64);
            sB += __shfl_xor(sB,16,64); qB += __shfl_xor(qB,16,64);
            sB += __shfl_xor(sB,32,64); qB += __shfl_xor(qB,32,64);
            float muA = sA*0.015625f, invA = rsqrtf(qA*0.015625f - muA*muA + 1e-5f);
            float muB = sB*0.015625f, invB = rsqrtf(qB*0.015625f - muB*muB + 1e-5f);
            f32x4 ga0 = PG4(0),  ga1 = PG4(16), ga2 = PG4(32), ga3 = PG4(48);
            f32x4 bb0 = PG4(64), bb1 = PG4(80), bb2 = PG4(96), bb3 = PG4(112);
            hA0 = mk8(lnq(xA0,muA,invA,ga0,bb0), lnq(xA1,muA,invA,ga1,bb1));
            hA1 = mk8(lnq(xA2,muA,invA,ga2,bb2), lnq(xA3,muA,invA,ga3,bb3));
            hB0 = mk8(lnq(xB0,muB,invB,ga0,bb0), lnq(xB1,muB,invB,ga1,bb1));
            hB1 = mk8(lnq(xB2,muB,invB,ga2,bb2), lnq(xB3,muB,invB,ga3,bb3));
        }

        // ---- attention: 4 heads, both tiles, weight frags shared ----
        uint2 oA0,oA1,oA2,oA3, oB0,oB1,oB2,oB3;
        attn_head2(WB, lane, fr, fg, hA0,hA1, hB0,hB1, 0, oA0, oB0);
        attn_head2(WB, lane, fr, fg, hA0,hA1, hB0,hB1, 1, oA1, oB1);
        attn_head2(WB, lane, fr, fg, hA0,hA1, hB0,hB1, 2, oA2, oB2);
        attn_head2(WB, lane, fr, fg, hA0,hA1, hB0,hB1, 3, oA3, oB3);

        // ---- proj + bp + residual 1 ----
        {
            bf16x8 oAlo = mk8(oA0,oA1), oAhi = mk8(oA2,oA3);
            bf16x8 oBlo = mk8(oB0,oB1), oBhi = mk8(oB2,oB3);
            #define PROJ(NT, XA, XB) { \
                bf16x8 wp0 = WFL(24+(NT)*2+0), wp1 = WFL(24+(NT)*2+1); \
                f32x4 pa = MFMA(wp0, oAlo, zf); pa = MFMA(wp1, oAhi, pa); \
                f32x4 pb = MFMA(wp0, oBlo, zf); pb = MFMA(wp1, oBhi, pb); \
                f32x4 bv = PG4(256 + 16*(NT)); \
                XA[0]+=pa[0]+bv[0]; XA[1]+=pa[1]+bv[1]; XA[2]+=pa[2]+bv[2]; XA[3]+=pa[3]+bv[3]; \
                XB[0]+=pb[0]+bv[0]; XB[1]+=pb[1]+bv[1]; XB[2]+=pb[2]+bv[2]; XB[3]+=pb[3]+bv[3]; }
            PROJ(0, xA0, xB0); PROJ(1, xA1, xB1); PROJ(2, xA2, xB2); PROJ(3, xA3, xB3);
            #undef PROJ
        }

        // ---- LN2 -> h2 fragments ----
        bf16x8 cA0, cA1, cB0, cB1;
        {
            float sA=0.f, qA=0.f, sB=0.f, qB=0.f;
            ACC4(sA,qA,xA0); ACC4(sA,qA,xA1); ACC4(sA,qA,xA2); ACC4(sA,qA,xA3);
            ACC4(sB,qB,xB0); ACC4(sB,qB,xB1); ACC4(sB,qB,xB2); ACC4(sB,qB,xB3);
            sA += __shfl_xor(sA,16,64); qA += __shfl_xor(qA,16,64);
            sA += __shfl_xor(sA,32,64); qA += __shfl_xor(qA,32,64);
            sB += __shfl_xor(sB,16,64); qB += __shfl_xor(qB,16,64);
            sB += __shfl_xor(sB,32,64); qB += __shfl_xor(qB,32,64);
            float muA = sA*0.015625f, invA = rsqrtf(qA*0.015625f - muA*muA + 1e-5f);
            float muB = sB*0.015625f, invB = rsqrtf(qB*0.015625f - muB*muB + 1e-5f);
            f32x4 ga0 = PG4(128), ga1 = PG4(144), ga2 = PG4(160), ga3 = PG4(176);
            f32x4 bb0 = PG4(192), bb1 = PG4(208), bb2 = PG4(224), bb3 = PG4(240);
            cA0 = mk8(lnq(xA0,muA,invA,ga0,bb0), lnq(xA1,muA,invA,ga1,bb1));
            cA1 = mk8(lnq(xA2,muA,invA,ga2,bb2), lnq(xA3,muA,invA,ga3,bb3));
            cB0 = mk8(lnq(xB0,muB,invB,ga0,bb0), lnq(xB1,muB,invB,ga1,bb1));
            cB1 = mk8(lnq(xB2,muB,invB,ga2,bb2), lnq(xB3,muB,invB,ga3,bb3));
        }

        // ---- MLP: W1/W2 frags shared across tiles ----
        f32x4 fA0=zf, fA1=zf, fA2=zf, fA3=zf, fB0=zf, fB1=zf, fB2=zf, fB3=zf;
        #pragma unroll
        for (int m2 = 0; m2 < 8; ++m2) {
            int t0 = 2*m2, t1 = 2*m2 + 1;
            bf16x8 w10 = WFL(32+t0*2+0), w11 = WFL(32+t0*2+1);
            f32x4 bi0 = PG4(384 + 16*t0);
            f32x4 aa = MFMA(w10, cA0, zf); aa = MFMA(w11, cA1, aa);
            f32x4 ab = MFMA(w10, cB0, zf); ab = MFMA(w11, cB1, ab);
            uint2 frA0 = relupack(aa, bi0), frB0 = relupack(ab, bi0);
            bf16x8 w12 = WFL(32+t1*2+0), w13 = WFL(32+t1*2+1);
            f32x4 bi1 = PG4(384 + 16*t1);
            f32x4 ac = MFMA(w12, cA0, zf); ac = MFMA(w13, cA1, ac);
            f32x4 ad = MFMA(w12, cB0, zf); ad = MFMA(w13, cB1, ad);
            uint2 frA1 = relupack(ac, bi1), frB1 = relupack(ad, bi1);
            bf16x8 ffrA = mk8(frA0, frA1), ffrB = mk8(frB0, frB1);
            bf16x8 w20 = WFL(64 + 0*8 + m2);
            fA0 = MFMA(w20, ffrA, fA0); fB0 = MFMA(w20, ffrB, fB0);
            bf16x8 w21 = WFL(64 + 1*8 + m2);
            fA1 = MFMA(w21, ffrA, fA1); fB1 = MFMA(w21, ffrB, fB1);
            bf16x8 w22 = WFL(64 + 2*8 + m2);
            fA2 = MFMA(w22, ffrA, fA2); fB2 = MFMA(w22, ffrB, fB2);
            bf16x8 w23 = WFL(64 + 3*8 + m2);
            fA3 = MFMA(w23, ffrA, fA3); fB3 = MFMA(w23, ffrB, fB3);
        }

        // ---- +b2, residual 2, store ----
        #define STORE(NT, XA, FA, XB, FB) { \
            f32x4 bv = PG4(320 + 16*(NT)); \
            f32x4 oa, obv; \
            oa[0]=XA[0]+FA[0]+bv[0]; oa[1]=XA[1]+FA[1]+bv[1]; \
            oa[2]=XA[2]+FA[2]+bv[2]; oa[3]=XA[3]+FA[3]+bv[3]; \
            obv[0]=XB[0]+FB[0]+bv[0]; obv[1]=XB[1]+FB[1]+bv[1]; \
            obv[2]=XB[2]+FB[2]+bv[2]; obv[3]=XB[3]+FB[3]+bv[3]; \
            *(f32x4*)(obp + xoff + 16*(NT)) = oa; \
            *(f32x4*)(obp + 1024 + xoff + 16*(NT)) = obv; }
        STORE(0, xA0, fA0, xB0, fB0); STORE(1, xA1, fA1, xB1, fB1);
        STORE(2, xA2, fA2, xB2, fB2); STORE(3, xA3, fA3, xB3, fB3);
        #undef STORE
        #undef ACC4
    }
    #undef PG4
}

extern "C" void kernel_launch(void* const* d_in, const int* in_sizes, int n_in,
                              void* d_out, int out_size, void* d_ws, size_t ws_size,
                              hipStream_t stream) {
    const float* x   = (const float*)d_in[0];
    const float* Wq  = (const float*)d_in[1];
    const float* Wk  = (const float*)d_in[2];
    const float* Wv  = (const float*)d_in[3];
    const float* Wp  = (const float*)d_in[4];
    const float* bp  = (const float*)d_in[5];
    const float* W1  = (const float*)d_in[6];
    const float* b1  = (const float*)d_in[7];
    const float* W2  = (const float*)d_in[8];
    const float* b2  = (const float*)d_in[9];
    const float* g1  = (const float*)d_in[10];
    const float* be1 = (const float*)d_in[11];
    const float* g2  = (const float*)d_in[12];
    const float* be2 = (const float*)d_in[13];
    int nPairs = in_sizes[0] / 1024;   // (B*T*C) / (2*8*64) = 32768
    fused_block<<<dim3(256), dim3(512), 0, stream>>>(
        x, Wq, Wk, Wv, Wp, bp, W1, b1, W2, b2, g1, be1, g2, be2,
        (float*)d_out, nPairs);
}

// Round 13
// 839.252 us; speedup vs baseline: 1.3562x; 1.0052x over previous
//
#include <hip/hip_runtime.h>
#include <hip/hip_bf16.h>
#include <stdint.h>

typedef __attribute__((ext_vector_type(8))) short bf16x8;
typedef __attribute__((ext_vector_type(4))) float f32x4;

// ALL-REGISTER, FULLY-SCALARIZED transformer block; 2 pairs (tiles A,B) per
// wave so each LDS weight-fragment read feeds 2 MFMAs.
//
// REGALLOC (rounds 3/9/10/11/12 evidence): hipcc's __launch_bounds__ 2nd arg
// acts as CUDA-style MIN BLOCKS PER CU. VGPR cap = 512 / (min_blocks *
// block_waves / 4). Observed: (512,2)->128, (512,4)->64, 768thr->84,
// 1024thr->64 -- all match. Our live set is ~200 VGPRs; any cap <=128 forces
// a spill loop (~1.6 GB scratch traffic, 5-8x slowdown). Fix: (512,1) ->
// 2 waves/SIMD -> 256-VGPR cap. LDS (100 KB) pins 1 WG/CU anyway, so the
// declared occupancy is exactly what the hardware gives us regardless.
//
// Transposed-chaining math identical to rounds 9-12 (PASSED, absmax 0.031):
// k = 8*fg+j <-> logical c = 16*(2m+u)+4*fg+(j&3), u=j>>2, applied to both
// register tiles and the weight pre-pack. x ownership: lane(fr,fg) owns row
// fr, cols 16*nt+4*fg+r. Each f32x4 global access covers 16 full 64-B
// sectors -> fully coalesced.
//
// LDS map (read-only after preload; no in-loop stores, no barriers):
//   [0, 98304)  96 weight fragments, bf16, frag f at byte f*1024 + lane*16:
//     f 0..23: QKV (f = sel*8 + hd*2 + m)   f 24..31: Wp^T
//     f 32..63: W1^T (f = 32 + t*2 + m)     f 64..95: W2^T (f = 64 + nt*8 + m)
//   [98304, 100864) params f32: g1@0 be1@64 g2@128 be2@192 bp@256 b2@320 b1@384

static __device__ __forceinline__ unsigned short f2bf(float f) {
    union { __hip_bfloat16 h; unsigned short u; } cv;
    cv.h = __float2bfloat16(f);
    return cv.u;
}
static __device__ __forceinline__ unsigned int f2bf2(float a, float b) {
    return (unsigned int)f2bf(a) | ((unsigned int)f2bf(b) << 16);
}
static __device__ __forceinline__ bf16x8 mk8(uint2 a, uint2 b) {
    union { uint4 u; bf16x8 v; } c;
    c.u = make_uint4(a.x, a.y, b.x, b.y);
    return c.v;
}
static __device__ __forceinline__ uint2 packbf(f32x4 a) {
    return make_uint2(f2bf2(a[0], a[1]), f2bf2(a[2], a[3]));
}
static __device__ __forceinline__ uint2 lnq(f32x4 x, float mu, float inv, f32x4 g, f32x4 b) {
    return make_uint2(f2bf2((x[0]-mu)*inv*g[0]+b[0], (x[1]-mu)*inv*g[1]+b[1]),
                      f2bf2((x[2]-mu)*inv*g[2]+b[2], (x[3]-mu)*inv*g[3]+b[3]));
}
static __device__ __forceinline__ uint2 relupack(f32x4 a, f32x4 b) {
    return make_uint2(f2bf2(fmaxf(a[0]+b[0],0.f), fmaxf(a[1]+b[1],0.f)),
                      f2bf2(fmaxf(a[2]+b[2],0.f), fmaxf(a[3]+b[3],0.f)));
}

#define MFMA(A,B,C) __builtin_amdgcn_mfma_f32_16x16x32_bf16((A),(B),(C),0,0,0)
#define WFL(F) (*(const bf16x8*)(WB + ((F) << 10) + (lane << 4)))

// softmax (masked exp, no max-sub: |s|<~2 by construction) + PV for one tile
static __device__ __forceinline__ uint2 soft_pv(f32x4 sa, uint2 vw, int fr, int fg) {
    const f32x4 zf = {0.f,0.f,0.f,0.f};
    const uint2 z2 = make_uint2(0u,0u);
    int tk0 = 4*fg, frq = fr & 7;
    bool v8 = ((fr ^ tk0) & 8) == 0;
    float p0 = (v8 && (((tk0+0)&7) <= frq)) ? __expf(sa[0]*0.125f) : 0.f;
    float p1 = (v8 && (((tk0+1)&7) <= frq)) ? __expf(sa[1]*0.125f) : 0.f;
    float p2 = (v8 && (((tk0+2)&7) <= frq)) ? __expf(sa[2]*0.125f) : 0.f;
    float p3 = (v8 && (((tk0+3)&7) <= frq)) ? __expf(sa[3]*0.125f) : 0.f;
    float rsum = p0 + p1 + p2 + p3;
    rsum += __shfl_xor(rsum, 16, 64);
    rsum += __shfl_xor(rsum, 32, 64);
    float pinv = __builtin_amdgcn_rcpf(rsum);
    uint2 pb = make_uint2(f2bf2(p0,p1), f2bf2(p2,p3));
    f32x4 oa = MFMA(mk8(vw, z2), mk8(pb, z2), zf);
    return make_uint2(f2bf2(oa[0]*pinv, oa[1]*pinv), f2bf2(oa[2]*pinv, oa[3]*pinv));
}

// one head, both tiles: weight frags loaded ONCE, used 2x
static __device__ __forceinline__ void attn_head2(
    const unsigned char* WB, int lane, int fr, int fg,
    bf16x8 hA0, bf16x8 hA1, bf16x8 hB0, bf16x8 hB1, int hd,
    uint2& oA, uint2& oB)
{
    const f32x4 zf = {0.f,0.f,0.f,0.f};
    const uint2 z2 = make_uint2(0u,0u);
    bf16x8 wq0 = WFL(hd*2+0),    wq1 = WFL(hd*2+1);
    bf16x8 wk0 = WFL(8+hd*2+0),  wk1 = WFL(8+hd*2+1);
    bf16x8 wv0 = WFL(16+hd*2+0), wv1 = WFL(16+hd*2+1);
    {   // tile A
        f32x4 qa = MFMA(wq0, hA0, zf); qa = MFMA(wq1, hA1, qa);
        f32x4 ka = MFMA(wk0, hA0, zf); ka = MFMA(wk1, hA1, ka);
        f32x4 va = MFMA(hA0, wv0, zf); va = MFMA(hA1, wv1, va);
        uint2 qw = packbf(qa), kw = packbf(ka), vw = packbf(va);
        f32x4 sa = MFMA(mk8(kw, z2), mk8(qw, z2), zf);
        oA = soft_pv(sa, vw, fr, fg);
    }
    {   // tile B
        f32x4 qa = MFMA(wq0, hB0, zf); qa = MFMA(wq1, hB1, qa);
        f32x4 ka = MFMA(wk0, hB0, zf); ka = MFMA(wk1, hB1, ka);
        f32x4 va = MFMA(hB0, wv0, zf); va = MFMA(hB1, wv1, va);
        uint2 qw = packbf(qa), kw = packbf(ka), vw = packbf(va);
        f32x4 sa = MFMA(mk8(kw, z2), mk8(qw, z2), zf);
        oB = soft_pv(sa, vw, fr, fg);
    }
}

__global__ __launch_bounds__(512, 1)
void fused_block(const float* __restrict__ xg,
                 const float* __restrict__ Wq, const float* __restrict__ Wk,
                 const float* __restrict__ Wv, const float* __restrict__ Wp,
                 const float* __restrict__ bp, const float* __restrict__ W1,
                 const float* __restrict__ b1, const float* __restrict__ W2,
                 const float* __restrict__ b2, const float* __restrict__ g1,
                 const float* __restrict__ be1, const float* __restrict__ g2,
                 const float* __restrict__ be2, float* __restrict__ out,
                 int nPairsTotal)
{
    __shared__ __align__(16) unsigned char LDS[100864];

    const int tid  = threadIdx.x;
    const int lane = tid & 63;
    const int wid  = tid >> 6;        // 0..7
    const int fr   = lane & 15;
    const int fg   = lane >> 4;

    // ---------------- weight pre-pack (identical math to round 9) -----------
    {
        unsigned short* lw = (unsigned short*)LDS;
        #pragma unroll 1
        for (int e = tid; e < 49152; e += 512) {
            int j = e & 7, ln = (e >> 3) & 63, f = e >> 9;
            int fr_ = ln & 15, fg_ = ln >> 4;
            int u = j >> 2, r_ = j & 3;
            float src;
            if (f < 24) {                 // QKV: f = sel*8 + hd*2 + m
                int sel = f >> 3, hd = (f >> 1) & 3, m = f & 1;
                int c = 16*(2*m + u) + 4*fg_ + r_;
                const float* W = (sel == 0) ? Wq : ((sel == 1) ? Wk : Wv);
                src = W[hd*1024 + c*16 + fr_];
            } else if (f < 32) {          // Wp^T
                int t = f - 24, nt = t >> 1, m = t & 1;
                int d = 16*(2*m + u) + 4*fg_ + r_;
                src = Wp[d*64 + 16*nt + fr_];
            } else if (f < 64) {          // W1^T
                int t = f - 32, tt = t >> 1, m = t & 1;
                int c = 16*(2*m + u) + 4*fg_ + r_;
                src = W1[c*256 + 16*tt + fr_];
            } else {                      // W2^T
                int t = f - 64, nt = t >> 3, m = t & 7;
                int n1 = 16*(2*m + u) + 4*fg_ + r_;
                src = W2[n1*64 + 16*nt + fr_];
            }
            lw[e] = f2bf(src);
        }
    }
    #pragma unroll 1
    for (int t = tid; t < 640; t += 512) {   // params
        float v;
        if      (t < 64)  v = g1[t];
        else if (t < 128) v = be1[t - 64];
        else if (t < 192) v = g2[t - 128];
        else if (t < 256) v = be2[t - 192];
        else if (t < 320) v = bp[t - 256];
        else if (t < 384) v = b2[t - 320];
        else              v = b1[t - 384];
        ((float*)(LDS + 98304))[t] = v;
    }
    __syncthreads();

    const unsigned char* WB = LDS;
    const float* PG = (const float*)(LDS + 98304);
    #define PG4(I) (*(const f32x4*)(PG + (I) + 4*fg))

    const int pipe = blockIdx.x * 8 + wid;    // 256*8 = 2048 pipes
    const f32x4 zf = {0.f, 0.f, 0.f, 0.f};
    const int xoff = fr*64 + 4*fg;
    const int nP2 = nPairsTotal >> 1;         // pair-pairs (16384)

    // prologue: prefetch first tile pair
    f32x4 nA0, nA1, nA2, nA3, nB0, nB1, nB2, nB3;
    if (pipe < nP2) {
        const float* xb0 = xg + (size_t)pipe * 2048;
        nA0 = *(const f32x4*)(xb0 + xoff);
        nA1 = *(const f32x4*)(xb0 + xoff + 16);
        nA2 = *(const f32x4*)(xb0 + xoff + 32);
        nA3 = *(const f32x4*)(xb0 + xoff + 48);
        nB0 = *(const f32x4*)(xb0 + 1024 + xoff);
        nB1 = *(const f32x4*)(xb0 + 1024 + xoff + 16);
        nB2 = *(const f32x4*)(xb0 + 1024 + xoff + 32);
        nB3 = *(const f32x4*)(xb0 + 1024 + xoff + 48);
    }

    #pragma unroll 1
    for (int gp2 = pipe; gp2 < nP2; gp2 += 2048) {
        float* obp = out + (size_t)gp2 * 2048;

        f32x4 xA0 = nA0, xA1 = nA1, xA2 = nA2, xA3 = nA3;
        f32x4 xB0 = nB0, xB1 = nB1, xB2 = nB2, xB3 = nB3;

        {   // next-tile prefetch, in flight across the iteration
            int gpn = gp2 + 2048;
            if (gpn < nP2) {
                const float* xbn = xg + (size_t)gpn * 2048;
                nA0 = *(const f32x4*)(xbn + xoff);
                nA1 = *(const f32x4*)(xbn + xoff + 16);
                nA2 = *(const f32x4*)(xbn + xoff + 32);
                nA3 = *(const f32x4*)(xbn + xoff + 48);
                nB0 = *(const f32x4*)(xbn + 1024 + xoff);
                nB1 = *(const f32x4*)(xbn + 1024 + xoff + 16);
                nB2 = *(const f32x4*)(xbn + 1024 + xoff + 32);
                nB3 = *(const f32x4*)(xbn + 1024 + xoff + 48);
            }
        }

        #define ACC4(S,SS,V) { S += V[0]+V[1]+V[2]+V[3]; \
                               SS += V[0]*V[0]+V[1]*V[1]+V[2]*V[2]+V[3]*V[3]; }

        // ---- LN1 (shared params) -> h fragments for A and B ----
        bf16x8 hA0, hA1, hB0, hB1;
        {
            float sA=0.f, qA=0.f, sB=0.f, qB=0.f;
            ACC4(sA,qA,xA0); ACC4(sA,qA,xA1); ACC4(sA,qA,xA2); ACC4(sA,qA,xA3);
            ACC4(sB,qB,xB0); ACC4(sB,qB,xB1); ACC4(sB,qB,xB2); ACC4(sB,qB,xB3);
            sA += __shfl_xor(sA,16,64); qA += __shfl_xor(qA,16,64);
            sA += __shfl_xor(sA,32,64); qA += __shfl_xor(qA,32,64);
            sB += __shfl_xor(sB,16,64); qB += __shfl_xor(qB,16,64);
            sB += __shfl_xor(sB,32,64); qB += __shfl_xor(qB,32,64);
            float muA = sA*0.015625f, invA = rsqrtf(qA*0.015625f - muA*muA + 1e-5f);
            float muB = sB*0.015625f, invB = rsqrtf(qB*0.015625f - muB*muB + 1e-5f);
            f32x4 ga0 = PG4(0),  ga1 = PG4(16), ga2 = PG4(32), ga3 = PG4(48);
            f32x4 bb0 = PG4(64), bb1 = PG4(80), bb2 = PG4(96), bb3 = PG4(112);
            hA0 = mk8(lnq(xA0,muA,invA,ga0,bb0), lnq(xA1,muA,invA,ga1,bb1));
            hA1 = mk8(lnq(xA2,muA,invA,ga2,bb2), lnq(xA3,muA,invA,ga3,bb3));
            hB0 = mk8(lnq(xB0,muB,invB,ga0,bb0), lnq(xB1,muB,invB,ga1,bb1));
            hB1 = mk8(lnq(xB2,muB,invB,ga2,bb2), lnq(xB3,muB,invB,ga3,bb3));
        }

        // ---- attention: 4 heads, both tiles, weight frags shared ----
        uint2 oA0,oA1,oA2,oA3, oB0,oB1,oB2,oB3;
        attn_head2(WB, lane, fr, fg, hA0,hA1, hB0,hB1, 0, oA0, oB0);
        attn_head2(WB, lane, fr, fg, hA0,hA1, hB0,hB1, 1, oA1, oB1);
        attn_head2(WB, lane, fr, fg, hA0,hA1, hB0,hB1, 2, oA2, oB2);
        attn_head2(WB, lane, fr, fg, hA0,hA1, hB0,hB1, 3, oA3, oB3);

        // ---- proj + bp + residual 1 ----
        {
            bf16x8 oAlo = mk8(oA0,oA1), oAhi = mk8(oA2,oA3);
            bf16x8 oBlo = mk8(oB0,oB1), oBhi = mk8(oB2,oB3);
            #define PROJ(NT, XA, XB) { \
                bf16x8 wp0 = WFL(24+(NT)*2+0), wp1 = WFL(24+(NT)*2+1); \
                f32x4 pa = MFMA(wp0, oAlo, zf); pa = MFMA(wp1, oAhi, pa); \
                f32x4 pb = MFMA(wp0, oBlo, zf); pb = MFMA(wp1, oBhi, pb); \
                f32x4 bv = PG4(256 + 16*(NT)); \
                XA[0]+=pa[0]+bv[0]; XA[1]+=pa[1]+bv[1]; XA[2]+=pa[2]+bv[2]; XA[3]+=pa[3]+bv[3]; \
                XB[0]+=pb[0]+bv[0]; XB[1]+=pb[1]+bv[1]; XB[2]+=pb[2]+bv[2]; XB[3]+=pb[3]+bv[3]; }
            PROJ(0, xA0, xB0); PROJ(1, xA1, xB1); PROJ(2, xA2, xB2); PROJ(3, xA3, xB3);
            #undef PROJ
        }

        // ---- LN2 -> h2 fragments ----
        bf16x8 cA0, cA1, cB0, cB1;
        {
            float sA=0.f, qA=0.f, sB=0.f, qB=0.f;
            ACC4(sA,qA,xA0); ACC4(sA,qA,xA1); ACC4(sA,qA,xA2); ACC4(sA,qA,xA3);
            ACC4(sB,qB,xB0); ACC4(sB,qB,xB1); ACC4(sB,qB,xB2); ACC4(sB,qB,xB3);
            sA += __shfl_xor(sA,16,64); qA += __shfl_xor(qA,16,64);
            sA += __shfl_xor(sA,32,64); qA += __shfl_xor(qA,32,64);
            sB += __shfl_xor(sB,16,64); qB += __shfl_xor(qB,16,64);
            sB += __shfl_xor(sB,32,64); qB += __shfl_xor(qB,32,64);
            float muA = sA*0.015625f, invA = rsqrtf(qA*0.015625f - muA*muA + 1e-5f);
            float muB = sB*0.015625f, invB = rsqrtf(qB*0.015625f - muB*muB + 1e-5f);
            f32x4 ga0 = PG4(128), ga1 = PG4(144), ga2 = PG4(160), ga3 = PG4(176);
            f32x4 bb0 = PG4(192), bb1 = PG4(208), bb2 = PG4(224), bb3 = PG4(240);
            cA0 = mk8(lnq(xA0,muA,invA,ga0,bb0), lnq(xA1,muA,invA,ga1,bb1));
            cA1 = mk8(lnq(xA2,muA,invA,ga2,bb2), lnq(xA3,muA,invA,ga3,bb3));
            cB0 = mk8(lnq(xB0,muB,invB,ga0,bb0), lnq(xB1,muB,invB,ga1,bb1));
            cB1 = mk8(lnq(xB2,muB,invB,ga2,bb2), lnq(xB3,muB,invB,ga3,bb3));
        }

        // ---- MLP: W1/W2 frags shared across tiles ----
        f32x4 fA0=zf, fA1=zf, fA2=zf, fA3=zf, fB0=zf, fB1=zf, fB2=zf, fB3=zf;
        #pragma unroll
        for (int m2 = 0; m2 < 8; ++m2) {
            int t0 = 2*m2, t1 = 2*m2 + 1;
            bf16x8 w10 = WFL(32+t0*2+0), w11 = WFL(32+t0*2+1);
            f32x4 bi0 = PG4(384 + 16*t0);
            f32x4 aa = MFMA(w10, cA0, zf); aa = MFMA(w11, cA1, aa);
            f32x4 ab = MFMA(w10, cB0, zf); ab = MFMA(w11, cB1, ab);
            uint2 frA0 = relupack(aa, bi0), frB0 = relupack(ab, bi0);
            bf16x8 w12 = WFL(32+t1*2+0), w13 = WFL(32+t1*2+1);
            f32x4 bi1 = PG4(384 + 16*t1);
            f32x4 ac = MFMA(w12, cA0, zf); ac = MFMA(w13, cA1, ac);
            f32x4 ad = MFMA(w12, cB0, zf); ad = MFMA(w13, cB1, ad);
            uint2 frA1 = relupack(ac, bi1), frB1 = relupack(ad, bi1);
            bf16x8 ffrA = mk8(frA0, frA1), ffrB = mk8(frB0, frB1);
            bf16x8 w20 = WFL(64 + 0*8 + m2);
            fA0 = MFMA(w20, ffrA, fA0); fB0 = MFMA(w20, ffrB, fB0);
            bf16x8 w21 = WFL(64 + 1*8 + m2);
            fA1 = MFMA(w21, ffrA, fA1); fB1 = MFMA(w21, ffrB, fB1);
            bf16x8 w22 = WFL(64 + 2*8 + m2);
            fA2 = MFMA(w22, ffrA, fA2); fB2 = MFMA(w22, ffrB, fB2);
            bf16x8 w23 = WFL(64 + 3*8 + m2);
            fA3 = MFMA(w23, ffrA, fA3); fB3 = MFMA(w23, ffrB, fB3);
        }

        // ---- +b2, residual 2, store ----
        #define STORE(NT, XA, FA, XB, FB) { \
            f32x4 bv = PG4(320 + 16*(NT)); \
            f32x4 oa, obv; \
            oa[0]=XA[0]+FA[0]+bv[0]; oa[1]=XA[1]+FA[1]+bv[1]; \
            oa[2]=XA[2]+FA[2]+bv[2]; oa[3]=XA[3]+FA[3]+bv[3]; \
            obv[0]=XB[0]+FB[0]+bv[0]; obv[1]=XB[1]+FB[1]+bv[1]; \
            obv[2]=XB[2]+FB[2]+bv[2]; obv[3]=XB[3]+FB[3]+bv[3]; \
            *(f32x4*)(obp + xoff + 16*(NT)) = oa; \
            *(f32x4*)(obp + 1024 + xoff + 16*(NT)) = obv; }
        STORE(0, xA0, fA0, xB0, fB0); STORE(1, xA1, fA1, xB1, fB1);
        STORE(2, xA2, fA2, xB2, fB2); STORE(3, xA3, fA3, xB3, fB3);
        #undef STORE
        #undef ACC4
    }
    #undef PG4
}

extern "C" void kernel_launch(void* const* d_in, const int* in_sizes, int n_in,
                              void* d_out, int out_size, void* d_ws, size_t ws_size,
                              hipStream_t stream) {
    const float* x   = (const float*)d_in[0];
    const float* Wq  = (const float*)d_in[1];
    const float* Wk  = (const float*)d_in[2];
    const float* Wv  = (const float*)d_in[3];
    const float* Wp  = (const float*)d_in[4];
    const float* bp  = (const float*)d_in[5];
    const float* W1  = (const float*)d_in[6];
    const float* b1  = (const float*)d_in[7];
    const float* W2  = (const float*)d_in[8];
    const float* b2  = (const float*)d_in[9];
    const float* g1  = (const float*)d_in[10];
    const float* be1 = (const float*)d_in[11];
    const float* g2  = (const float*)d_in[12];
    const float* be2 = (const float*)d_in[13];
    int nPairs = in_sizes[0] / 1024;   // (B*T*C) / (2*8*64) = 32768
    fused_block<<<dim3(256), dim3(512), 0, stream>>>(
        x, Wq, Wk, Wv, Wp, bp, W1, b1, W2, b2, g1, be1, g2, be2,
        (float*)d_out, nPairs);
}

// Round 14
// 627.716 us; speedup vs baseline: 1.8132x; 1.3370x over previous
//
#include <hip/hip_runtime.h>
#include <hip/hip_bf16.h>
#include <stdint.h>

typedef __attribute__((ext_vector_type(8))) short bf16x8;
typedef __attribute__((ext_vector_type(4))) float f32x4;

// ALL-REGISTER transformer block, ONE pair (16 rows) per wave.
//
// REGALLOC (rounds 9-13 evidence): 512-thread kernels get a hard 128-VGPR
// ceiling on this toolchain regardless of __launch_bounds__ 2nd arg /
// amdgpu_waves_per_eu. The 2-pair design (~150-200 live values) spilled ~60
// values -> 1.6 GB scratch traffic. Fix: halve the live set (1 pair/wave,
// ~90-110 values) so demand < 128. LDS weight reads become the limiting
// pipe (~96 KB/wave-iter), est. ~60us vs HBM floor 43us.
//
// Transposed-chaining math identical to rounds 9-13 (PASSED, absmax 0.031):
// k = 8*fg+j <-> logical c = 16*(2m+u)+4*fg+(j&3), u=j>>2, applied to both
// register tiles and the weight pre-pack. x ownership: lane(fr,fg) owns row
// fr, cols 16*nt+4*fg+r. Each f32x4 global access covers 16 full 64-B
// sectors -> fully coalesced.
//
// LDS map (read-only after preload; no in-loop stores, no barriers):
//   [0, 98304)  96 weight fragments, bf16, frag f at byte f*1024 + lane*16:
//     f 0..23: QKV (f = sel*8 + hd*2 + m)   f 24..31: Wp^T
//     f 32..63: W1^T (f = 32 + t*2 + m)     f 64..95: W2^T (f = 64 + nt*8 + m)
//   [98304, 100864) params f32: g1@0 be1@64 g2@128 be2@192 bp@256 b2@320 b1@384

static __device__ __forceinline__ unsigned short f2bf(float f) {
    union { __hip_bfloat16 h; unsigned short u; } cv;
    cv.h = __float2bfloat16(f);
    return cv.u;
}
static __device__ __forceinline__ unsigned int f2bf2(float a, float b) {
    return (unsigned int)f2bf(a) | ((unsigned int)f2bf(b) << 16);
}
static __device__ __forceinline__ bf16x8 mk8(uint2 a, uint2 b) {
    union { uint4 u; bf16x8 v; } c;
    c.u = make_uint4(a.x, a.y, b.x, b.y);
    return c.v;
}
static __device__ __forceinline__ uint2 packbf(f32x4 a) {
    return make_uint2(f2bf2(a[0], a[1]), f2bf2(a[2], a[3]));
}
static __device__ __forceinline__ uint2 lnq(f32x4 x, float mu, float inv, f32x4 g, f32x4 b) {
    return make_uint2(f2bf2((x[0]-mu)*inv*g[0]+b[0], (x[1]-mu)*inv*g[1]+b[1]),
                      f2bf2((x[2]-mu)*inv*g[2]+b[2], (x[3]-mu)*inv*g[3]+b[3]));
}
static __device__ __forceinline__ uint2 relupack(f32x4 a, f32x4 b) {
    return make_uint2(f2bf2(fmaxf(a[0]+b[0],0.f), fmaxf(a[1]+b[1],0.f)),
                      f2bf2(fmaxf(a[2]+b[2],0.f), fmaxf(a[3]+b[3],0.f)));
}

#define MFMA(A,B,C) __builtin_amdgcn_mfma_f32_16x16x32_bf16((A),(B),(C),0,0,0)

// QK^T scores -> masked exp (no max-sub: |s|<~2 by construction) -> PV.
// Lane holds S[tq=fr][tk=4fg+r]; rowsum across fg via xor 16,32.
static __device__ __forceinline__ uint2 attn_tail(f32x4 sa, uint2 vw, int fr, int fg) {
    const f32x4 zf = {0.f,0.f,0.f,0.f};
    const uint2 z2 = make_uint2(0u,0u);
    int tk0 = 4*fg, frq = fr & 7;
    bool v8 = ((fr ^ tk0) & 8) == 0;
    float p0 = (v8 && (((tk0+0)&7) <= frq)) ? __expf(sa[0]*0.125f) : 0.f;
    float p1 = (v8 && (((tk0+1)&7) <= frq)) ? __expf(sa[1]*0.125f) : 0.f;
    float p2 = (v8 && (((tk0+2)&7) <= frq)) ? __expf(sa[2]*0.125f) : 0.f;
    float p3 = (v8 && (((tk0+3)&7) <= frq)) ? __expf(sa[3]*0.125f) : 0.f;
    float rsum = p0 + p1 + p2 + p3;
    rsum += __shfl_xor(rsum, 16, 64);
    rsum += __shfl_xor(rsum, 32, 64);
    float pinv = __builtin_amdgcn_rcpf(rsum);
    uint2 pb = make_uint2(f2bf2(p0,p1), f2bf2(p2,p3));
    f32x4 oa = MFMA(mk8(vw, z2), mk8(pb, z2), zf);
    return make_uint2(f2bf2(oa[0]*pinv, oa[1]*pinv), f2bf2(oa[2]*pinv, oa[3]*pinv));
}

// One attention head for one 16-row tile; weight frags passed by value.
static __device__ __forceinline__ uint2 attn_head(
    bf16x8 wq0, bf16x8 wq1, bf16x8 wk0, bf16x8 wk1, bf16x8 wv0, bf16x8 wv1,
    bf16x8 h0, bf16x8 h1, int fr, int fg)
{
    const f32x4 zf = {0.f,0.f,0.f,0.f};
    const uint2 z2 = make_uint2(0u,0u);
    f32x4 qa = MFMA(wq0, h0, zf); qa = MFMA(wq1, h1, qa);
    f32x4 ka = MFMA(wk0, h0, zf); ka = MFMA(wk1, h1, ka);
    f32x4 va = MFMA(h0, wv0, zf); va = MFMA(h1, wv1, va);
    uint2 qw = packbf(qa), kw = packbf(ka), vw = packbf(va);
    f32x4 sa = MFMA(mk8(kw, z2), mk8(qw, z2), zf);
    return attn_tail(sa, vw, fr, fg);
}

__global__ __launch_bounds__(512, 1)
void fused_block(const float* __restrict__ xg,
                 const float* __restrict__ Wq, const float* __restrict__ Wk,
                 const float* __restrict__ Wv, const float* __restrict__ Wp,
                 const float* __restrict__ bp, const float* __restrict__ W1,
                 const float* __restrict__ b1, const float* __restrict__ W2,
                 const float* __restrict__ b2, const float* __restrict__ g1,
                 const float* __restrict__ be1, const float* __restrict__ g2,
                 const float* __restrict__ be2, float* __restrict__ out,
                 int nPairsTotal)
{
    __shared__ __align__(16) unsigned char LDS[100864];

    const int tid  = threadIdx.x;
    const int lane = tid & 63;
    const int wid  = tid >> 6;        // 0..7
    const int fr   = lane & 15;
    const int fg   = lane >> 4;

    // ---------------- weight pre-pack (identical math to round 9) -----------
    {
        unsigned short* lw = (unsigned short*)LDS;
        #pragma unroll 1
        for (int e = tid; e < 49152; e += 512) {
            int j = e & 7, ln = (e >> 3) & 63, f = e >> 9;
            int fr_ = ln & 15, fg_ = ln >> 4;
            int u = j >> 2, r_ = j & 3;
            float src;
            if (f < 24) {                 // QKV: f = sel*8 + hd*2 + m
                int sel = f >> 3, hd = (f >> 1) & 3, m = f & 1;
                int c = 16*(2*m + u) + 4*fg_ + r_;
                const float* W = (sel == 0) ? Wq : ((sel == 1) ? Wk : Wv);
                src = W[hd*1024 + c*16 + fr_];
            } else if (f < 32) {          // Wp^T
                int t = f - 24, nt = t >> 1, m = t & 1;
                int d = 16*(2*m + u) + 4*fg_ + r_;
                src = Wp[d*64 + 16*nt + fr_];
            } else if (f < 64) {          // W1^T
                int t = f - 32, tt = t >> 1, m = t & 1;
                int c = 16*(2*m + u) + 4*fg_ + r_;
                src = W1[c*256 + 16*tt + fr_];
            } else {                      // W2^T
                int t = f - 64, nt = t >> 3, m = t & 7;
                int n1 = 16*(2*m + u) + 4*fg_ + r_;
                src = W2[n1*64 + 16*nt + fr_];
            }
            lw[e] = f2bf(src);
        }
    }
    #pragma unroll 1
    for (int t = tid; t < 640; t += 512) {   // params
        float v;
        if      (t < 64)  v = g1[t];
        else if (t < 128) v = be1[t - 64];
        else if (t < 192) v = g2[t - 128];
        else if (t < 256) v = be2[t - 192];
        else if (t < 320) v = bp[t - 256];
        else if (t < 384) v = b2[t - 320];
        else              v = b1[t - 384];
        ((float*)(LDS + 98304))[t] = v;
    }
    __syncthreads();

    const float* PG = (const float*)(LDS + 98304);
    #define WFL(F) (*(const bf16x8*)(LDS + ((F) << 10) + (lane << 4)))
    #define PG4(I) (*(const f32x4*)(PG + (I) + 4*fg))

    const int pipe = blockIdx.x * 8 + wid;    // 256*8 = 2048 pipes
    const f32x4 zf = {0.f, 0.f, 0.f, 0.f};
    const int xoff = fr*64 + 4*fg;

    // prologue: prefetch first tile
    f32x4 n0, n1, n2, n3;
    if (pipe < nPairsTotal) {
        const float* xb0 = xg + (size_t)pipe * 1024;
        n0 = *(const f32x4*)(xb0 + xoff);
        n1 = *(const f32x4*)(xb0 + xoff + 16);
        n2 = *(const f32x4*)(xb0 + xoff + 32);
        n3 = *(const f32x4*)(xb0 + xoff + 48);
    }

    #pragma unroll 1
    for (int gp = pipe; gp < nPairsTotal; gp += 2048) {
        float* obp = out + (size_t)gp * 1024;

        f32x4 xv0 = n0, xv1 = n1, xv2 = n2, xv3 = n3;

        {   // next-tile prefetch, in flight across the iteration
            int gpn = gp + 2048;
            if (gpn < nPairsTotal) {
                const float* xbn = xg + (size_t)gpn * 1024;
                n0 = *(const f32x4*)(xbn + xoff);
                n1 = *(const f32x4*)(xbn + xoff + 16);
                n2 = *(const f32x4*)(xbn + xoff + 32);
                n3 = *(const f32x4*)(xbn + xoff + 48);
            }
        }

        #define ACC4(S,SS,V) { S += V[0]+V[1]+V[2]+V[3]; \
                               SS += V[0]*V[0]+V[1]*V[1]+V[2]*V[2]+V[3]*V[3]; }

        // ---- LN1 (row = fr; reduce across fg via xor 16,32) -> h frags ----
        bf16x8 hf0, hf1;
        {
            float s = 0.f, q = 0.f;
            ACC4(s,q,xv0); ACC4(s,q,xv1); ACC4(s,q,xv2); ACC4(s,q,xv3);
            s += __shfl_xor(s,16,64); q += __shfl_xor(q,16,64);
            s += __shfl_xor(s,32,64); q += __shfl_xor(q,32,64);
            float mu  = s * 0.015625f;
            float inv = rsqrtf(q * 0.015625f - mu*mu + 1e-5f);
            hf0 = mk8(lnq(xv0,mu,inv,PG4(0),  PG4(64)),
                      lnq(xv1,mu,inv,PG4(16), PG4(80)));
            hf1 = mk8(lnq(xv2,mu,inv,PG4(32), PG4(96)),
                      lnq(xv3,mu,inv,PG4(48), PG4(112)));
        }

        // ---- attention: 4 heads ----
        uint2 o0, o1, o2, o3;
        o0 = attn_head(WFL(0), WFL(1), WFL(8),  WFL(9),  WFL(16), WFL(17), hf0, hf1, fr, fg);
        o1 = attn_head(WFL(2), WFL(3), WFL(10), WFL(11), WFL(18), WFL(19), hf0, hf1, fr, fg);
        o2 = attn_head(WFL(4), WFL(5), WFL(12), WFL(13), WFL(20), WFL(21), hf0, hf1, fr, fg);
        o3 = attn_head(WFL(6), WFL(7), WFL(14), WFL(15), WFL(22), WFL(23), hf0, hf1, fr, fg);

        // ---- proj: sa^T = Wp^T O^T (+bp), residual into xv ----
        {
            bf16x8 olo = mk8(o0, o1), ohi = mk8(o2, o3);
            #define PROJ(NT, XV) { \
                f32x4 pa = MFMA(WFL(24+(NT)*2+0), olo, zf); \
                pa       = MFMA(WFL(24+(NT)*2+1), ohi, pa); \
                f32x4 bv = PG4(256 + 16*(NT)); \
                XV[0]+=pa[0]+bv[0]; XV[1]+=pa[1]+bv[1]; \
                XV[2]+=pa[2]+bv[2]; XV[3]+=pa[3]+bv[3]; }
            PROJ(0, xv0); PROJ(1, xv1); PROJ(2, xv2); PROJ(3, xv3);
            #undef PROJ
        }

        // ---- LN2 -> h2 frags ----
        bf16x8 cf0, cf1;
        {
            float s = 0.f, q = 0.f;
            ACC4(s,q,xv0); ACC4(s,q,xv1); ACC4(s,q,xv2); ACC4(s,q,xv3);
            s += __shfl_xor(s,16,64); q += __shfl_xor(q,16,64);
            s += __shfl_xor(s,32,64); q += __shfl_xor(q,32,64);
            float mu  = s * 0.015625f;
            float inv = rsqrtf(q * 0.015625f - mu*mu + 1e-5f);
            cf0 = mk8(lnq(xv0,mu,inv,PG4(128), PG4(192)),
                      lnq(xv1,mu,inv,PG4(144), PG4(208)));
            cf1 = mk8(lnq(xv2,mu,inv,PG4(160), PG4(224)),
                      lnq(xv3,mu,inv,PG4(176), PG4(240)));
        }

        // ---- MLP: ff1^T = W1^T h2^T (relu,+b1) feeds ff2^T = W2^T ff1^T ----
        f32x4 fa0 = zf, fa1 = zf, fa2 = zf, fa3 = zf;
        #pragma unroll
        for (int m2 = 0; m2 < 8; ++m2) {
            int t0 = 2*m2, t1 = 2*m2 + 1;
            f32x4 aa = MFMA(WFL(32+t0*2+0), cf0, zf);
            aa       = MFMA(WFL(32+t0*2+1), cf1, aa);
            uint2 fr0 = relupack(aa, PG4(384 + 16*t0));
            f32x4 ac = MFMA(WFL(32+t1*2+0), cf0, zf);
            ac       = MFMA(WFL(32+t1*2+1), cf1, ac);
            uint2 fr1 = relupack(ac, PG4(384 + 16*t1));
            bf16x8 ffr = mk8(fr0, fr1);
            fa0 = MFMA(WFL(64 + 0*8 + m2), ffr, fa0);
            fa1 = MFMA(WFL(64 + 1*8 + m2), ffr, fa1);
            fa2 = MFMA(WFL(64 + 2*8 + m2), ffr, fa2);
            fa3 = MFMA(WFL(64 + 3*8 + m2), ffr, fa3);
        }

        // ---- +b2, residual 2, store ----
        #define STORE(NT, XV, FA) { \
            f32x4 bv = PG4(320 + 16*(NT)); \
            f32x4 o; \
            o[0]=XV[0]+FA[0]+bv[0]; o[1]=XV[1]+FA[1]+bv[1]; \
            o[2]=XV[2]+FA[2]+bv[2]; o[3]=XV[3]+FA[3]+bv[3]; \
            *(f32x4*)(obp + xoff + 16*(NT)) = o; }
        STORE(0, xv0, fa0); STORE(1, xv1, fa1);
        STORE(2, xv2, fa2); STORE(3, xv3, fa3);
        #undef STORE
        #undef ACC4
    }
    #undef WFL
    #undef PG4
}

extern "C" void kernel_launch(void* const* d_in, const int* in_sizes, int n_in,
                              void* d_out, int out_size, void* d_ws, size_t ws_size,
                              hipStream_t stream) {
    const float* x   = (const float*)d_in[0];
    const float* Wq  = (const float*)d_in[1];
    const float* Wk  = (const float*)d_in[2];
    const float* Wv  = (const float*)d_in[3];
    const float* Wp  = (const float*)d_in[4];
    const float* bp  = (const float*)d_in[5];
    const float* W1  = (const float*)d_in[6];
    const float* b1  = (const float*)d_in[7];
    const float* W2  = (const float*)d_in[8];
    const float* b2  = (const float*)d_in[9];
    const float* g1  = (const float*)d_in[10];
    const float* be1 = (const float*)d_in[11];
    const float* g2  = (const float*)d_in[12];
    const float* be2 = (const float*)d_in[13];
    int nPairs = in_sizes[0] / 1024;   // (B*T*C) / (2*8*64) = 32768
    fused_block<<<dim3(256), dim3(512), 0, stream>>>(
        x, Wq, Wk, Wv, Wp, bp, W1, b1, W2, b2, g1, be1, g2, be2,
        (float*)d_out, nPairs);
}

// Round 15
// 121.259 us; speedup vs baseline: 9.3864x; 5.1767x over previous
//
#include <hip/hip_runtime.h>
#include <hip/hip_bf16.h>
#include <stdint.h>

typedef __attribute__((ext_vector_type(8))) short bf16x8;
typedef __attribute__((ext_vector_type(4))) float f32x4;

// ALL-REGISTER transformer block, ONE pair (16 rows) per wave, with
// SCHEDULER FENCES. Rounds 9-14 lesson chain: (1) 512-thread kernels get a
// hard 128-VGPR cap on this toolchain (launch_bounds 2nd arg / waves_per_eu
// do NOT raise it); (2) named-value demand ~100 fits, BUT the pre-RA
// scheduler hoists ds_read_b128 weight fragments across phases (fully
// unrolled MLP exposes 64 loads = 256 VGPRs of results) -> allocator spills
// the hoisted values -> 1.4 GB scratch reload traffic. Fix: sched_barrier(0)
// at every phase boundary + #pragma unroll 1 on the MLP loop bounds the
// hoisting window to one phase (~50 transient regs).
//
// Transposed-chaining math identical to rounds 9-14 (PASSED, absmax 0.031):
// k = 8*fg+j <-> logical c = 16*(2m+u)+4*fg+(j&3), u=j>>2, applied to both
// register tiles and the weight pre-pack. x ownership: lane(fr,fg) owns row
// fr, cols 16*nt+4*fg+r. Each f32x4 global access covers 16 full 64-B
// sectors -> fully coalesced.
//
// LDS map (read-only after preload; no in-loop stores, no barriers):
//   [0, 98304)  96 weight fragments, bf16, frag f at byte f*1024 + lane*16:
//     f 0..23: QKV (f = sel*8 + hd*2 + m)   f 24..31: Wp^T
//     f 32..63: W1^T (f = 32 + t*2 + m)     f 64..95: W2^T (f = 64 + nt*8 + m)
//   [98304, 100864) params f32: g1@0 be1@64 g2@128 be2@192 bp@256 b2@320 b1@384

static __device__ __forceinline__ unsigned short f2bf(float f) {
    union { __hip_bfloat16 h; unsigned short u; } cv;
    cv.h = __float2bfloat16(f);
    return cv.u;
}
static __device__ __forceinline__ unsigned int f2bf2(float a, float b) {
    return (unsigned int)f2bf(a) | ((unsigned int)f2bf(b) << 16);
}
static __device__ __forceinline__ bf16x8 mk8(uint2 a, uint2 b) {
    union { uint4 u; bf16x8 v; } c;
    c.u = make_uint4(a.x, a.y, b.x, b.y);
    return c.v;
}
static __device__ __forceinline__ uint2 packbf(f32x4 a) {
    return make_uint2(f2bf2(a[0], a[1]), f2bf2(a[2], a[3]));
}
static __device__ __forceinline__ uint2 lnq(f32x4 x, float mu, float inv, f32x4 g, f32x4 b) {
    return make_uint2(f2bf2((x[0]-mu)*inv*g[0]+b[0], (x[1]-mu)*inv*g[1]+b[1]),
                      f2bf2((x[2]-mu)*inv*g[2]+b[2], (x[3]-mu)*inv*g[3]+b[3]));
}
static __device__ __forceinline__ uint2 relupack(f32x4 a, f32x4 b) {
    return make_uint2(f2bf2(fmaxf(a[0]+b[0],0.f), fmaxf(a[1]+b[1],0.f)),
                      f2bf2(fmaxf(a[2]+b[2],0.f), fmaxf(a[3]+b[3],0.f)));
}

#define MFMA(A,B,C) __builtin_amdgcn_mfma_f32_16x16x32_bf16((A),(B),(C),0,0,0)
#define SB() __builtin_amdgcn_sched_barrier(0)

// QK^T scores -> masked exp (no max-sub: |s|<~2 by construction) -> PV.
// Lane holds S[tq=fr][tk=4fg+r]; rowsum across fg via xor 16,32.
static __device__ __forceinline__ uint2 attn_tail(f32x4 sa, uint2 vw, int fr, int fg) {
    const f32x4 zf = {0.f,0.f,0.f,0.f};
    const uint2 z2 = make_uint2(0u,0u);
    int tk0 = 4*fg, frq = fr & 7;
    bool v8 = ((fr ^ tk0) & 8) == 0;
    float p0 = (v8 && (((tk0+0)&7) <= frq)) ? __expf(sa[0]*0.125f) : 0.f;
    float p1 = (v8 && (((tk0+1)&7) <= frq)) ? __expf(sa[1]*0.125f) : 0.f;
    float p2 = (v8 && (((tk0+2)&7) <= frq)) ? __expf(sa[2]*0.125f) : 0.f;
    float p3 = (v8 && (((tk0+3)&7) <= frq)) ? __expf(sa[3]*0.125f) : 0.f;
    float rsum = p0 + p1 + p2 + p3;
    rsum += __shfl_xor(rsum, 16, 64);
    rsum += __shfl_xor(rsum, 32, 64);
    float pinv = __builtin_amdgcn_rcpf(rsum);
    uint2 pb = make_uint2(f2bf2(p0,p1), f2bf2(p2,p3));
    f32x4 oa = MFMA(mk8(vw, z2), mk8(pb, z2), zf);
    return make_uint2(f2bf2(oa[0]*pinv, oa[1]*pinv), f2bf2(oa[2]*pinv, oa[3]*pinv));
}

// One attention head for one 16-row tile; weight frags passed by value.
static __device__ __forceinline__ uint2 attn_head(
    bf16x8 wq0, bf16x8 wq1, bf16x8 wk0, bf16x8 wk1, bf16x8 wv0, bf16x8 wv1,
    bf16x8 h0, bf16x8 h1, int fr, int fg)
{
    const f32x4 zf = {0.f,0.f,0.f,0.f};
    const uint2 z2 = make_uint2(0u,0u);
    f32x4 qa = MFMA(wq0, h0, zf); qa = MFMA(wq1, h1, qa);
    f32x4 ka = MFMA(wk0, h0, zf); ka = MFMA(wk1, h1, ka);
    f32x4 va = MFMA(h0, wv0, zf); va = MFMA(h1, wv1, va);
    uint2 qw = packbf(qa), kw = packbf(ka), vw = packbf(va);
    f32x4 sa = MFMA(mk8(kw, z2), mk8(qw, z2), zf);
    return attn_tail(sa, vw, fr, fg);
}

__global__ __launch_bounds__(512, 1)
void fused_block(const float* __restrict__ xg,
                 const float* __restrict__ Wq, const float* __restrict__ Wk,
                 const float* __restrict__ Wv, const float* __restrict__ Wp,
                 const float* __restrict__ bp, const float* __restrict__ W1,
                 const float* __restrict__ b1, const float* __restrict__ W2,
                 const float* __restrict__ b2, const float* __restrict__ g1,
                 const float* __restrict__ be1, const float* __restrict__ g2,
                 const float* __restrict__ be2, float* __restrict__ out,
                 int nPairsTotal)
{
    __shared__ __align__(16) unsigned char LDS[100864];

    const int tid  = threadIdx.x;
    const int lane = tid & 63;
    const int wid  = tid >> 6;        // 0..7
    const int fr   = lane & 15;
    const int fg   = lane >> 4;

    // ---------------- weight pre-pack (identical math to round 9) -----------
    {
        unsigned short* lw = (unsigned short*)LDS;
        #pragma unroll 1
        for (int e = tid; e < 49152; e += 512) {
            int j = e & 7, ln = (e >> 3) & 63, f = e >> 9;
            int fr_ = ln & 15, fg_ = ln >> 4;
            int u = j >> 2, r_ = j & 3;
            float src;
            if (f < 24) {                 // QKV: f = sel*8 + hd*2 + m
                int sel = f >> 3, hd = (f >> 1) & 3, m = f & 1;
                int c = 16*(2*m + u) + 4*fg_ + r_;
                const float* W = (sel == 0) ? Wq : ((sel == 1) ? Wk : Wv);
                src = W[hd*1024 + c*16 + fr_];
            } else if (f < 32) {          // Wp^T
                int t = f - 24, nt = t >> 1, m = t & 1;
                int d = 16*(2*m + u) + 4*fg_ + r_;
                src = Wp[d*64 + 16*nt + fr_];
            } else if (f < 64) {          // W1^T
                int t = f - 32, tt = t >> 1, m = t & 1;
                int c = 16*(2*m + u) + 4*fg_ + r_;
                src = W1[c*256 + 16*tt + fr_];
            } else {                      // W2^T
                int t = f - 64, nt = t >> 3, m = t & 7;
                int n1 = 16*(2*m + u) + 4*fg_ + r_;
                src = W2[n1*64 + 16*nt + fr_];
            }
            lw[e] = f2bf(src);
        }
    }
    #pragma unroll 1
    for (int t = tid; t < 640; t += 512) {   // params
        float v;
        if      (t < 64)  v = g1[t];
        else if (t < 128) v = be1[t - 64];
        else if (t < 192) v = g2[t - 128];
        else if (t < 256) v = be2[t - 192];
        else if (t < 320) v = bp[t - 256];
        else if (t < 384) v = b2[t - 320];
        else              v = b1[t - 384];
        ((float*)(LDS + 98304))[t] = v;
    }
    __syncthreads();

    const float* PG = (const float*)(LDS + 98304);
    #define WFL(F) (*(const bf16x8*)(LDS + ((F) << 10) + (lane << 4)))
    #define PG4(I) (*(const f32x4*)(PG + (I) + 4*fg))

    const int pipe = blockIdx.x * 8 + wid;    // 256*8 = 2048 pipes
    const f32x4 zf = {0.f, 0.f, 0.f, 0.f};
    const int xoff = fr*64 + 4*fg;

    // prologue: prefetch first tile
    f32x4 n0, n1, n2, n3;
    if (pipe < nPairsTotal) {
        const float* xb0 = xg + (size_t)pipe * 1024;
        n0 = *(const f32x4*)(xb0 + xoff);
        n1 = *(const f32x4*)(xb0 + xoff + 16);
        n2 = *(const f32x4*)(xb0 + xoff + 32);
        n3 = *(const f32x4*)(xb0 + xoff + 48);
    }

    #pragma unroll 1
    for (int gp = pipe; gp < nPairsTotal; gp += 2048) {
        float* obp = out + (size_t)gp * 1024;

        f32x4 xv0 = n0, xv1 = n1, xv2 = n2, xv3 = n3;

        {   // next-tile prefetch, in flight across the iteration
            int gpn = gp + 2048;
            if (gpn < nPairsTotal) {
                const float* xbn = xg + (size_t)gpn * 1024;
                n0 = *(const f32x4*)(xbn + xoff);
                n1 = *(const f32x4*)(xbn + xoff + 16);
                n2 = *(const f32x4*)(xbn + xoff + 32);
                n3 = *(const f32x4*)(xbn + xoff + 48);
            }
        }
        SB();   // prefetch issued; nothing below may hoist above this point

        #define ACC4(S,SS,V) { S += V[0]+V[1]+V[2]+V[3]; \
                               SS += V[0]*V[0]+V[1]*V[1]+V[2]*V[2]+V[3]*V[3]; }

        // ---- LN1 (row = fr; reduce across fg via xor 16,32) -> h frags ----
        bf16x8 hf0, hf1;
        {
            float s = 0.f, q = 0.f;
            ACC4(s,q,xv0); ACC4(s,q,xv1); ACC4(s,q,xv2); ACC4(s,q,xv3);
            s += __shfl_xor(s,16,64); q += __shfl_xor(q,16,64);
            s += __shfl_xor(s,32,64); q += __shfl_xor(q,32,64);
            float mu  = s * 0.015625f;
            float inv = rsqrtf(q * 0.015625f - mu*mu + 1e-5f);
            hf0 = mk8(lnq(xv0,mu,inv,PG4(0),  PG4(64)),
                      lnq(xv1,mu,inv,PG4(16), PG4(80)));
            hf1 = mk8(lnq(xv2,mu,inv,PG4(32), PG4(96)),
                      lnq(xv3,mu,inv,PG4(48), PG4(112)));
        }
        SB();

        // ---- attention: 4 heads, fenced so loads stay within their phase ----
        uint2 o0, o1, o2, o3;
        o0 = attn_head(WFL(0), WFL(1), WFL(8),  WFL(9),  WFL(16), WFL(17), hf0, hf1, fr, fg);
        SB();
        o1 = attn_head(WFL(2), WFL(3), WFL(10), WFL(11), WFL(18), WFL(19), hf0, hf1, fr, fg);
        SB();
        o2 = attn_head(WFL(4), WFL(5), WFL(12), WFL(13), WFL(20), WFL(21), hf0, hf1, fr, fg);
        SB();
        o3 = attn_head(WFL(6), WFL(7), WFL(14), WFL(15), WFL(22), WFL(23), hf0, hf1, fr, fg);
        SB();

        // ---- proj: sa^T = Wp^T O^T (+bp), residual into xv ----
        {
            bf16x8 olo = mk8(o0, o1), ohi = mk8(o2, o3);
            #define PROJ(NT, XV) { \
                f32x4 pa = MFMA(WFL(24+(NT)*2+0), olo, zf); \
                pa       = MFMA(WFL(24+(NT)*2+1), ohi, pa); \
                f32x4 bv = PG4(256 + 16*(NT)); \
                XV[0]+=pa[0]+bv[0]; XV[1]+=pa[1]+bv[1]; \
                XV[2]+=pa[2]+bv[2]; XV[3]+=pa[3]+bv[3]; }
            PROJ(0, xv0); PROJ(1, xv1); PROJ(2, xv2); PROJ(3, xv3);
            #undef PROJ
        }
        SB();

        // ---- LN2 -> h2 frags ----
        bf16x8 cf0, cf1;
        {
            float s = 0.f, q = 0.f;
            ACC4(s,q,xv0); ACC4(s,q,xv1); ACC4(s,q,xv2); ACC4(s,q,xv3);
            s += __shfl_xor(s,16,64); q += __shfl_xor(q,16,64);
            s += __shfl_xor(s,32,64); q += __shfl_xor(q,32,64);
            float mu  = s * 0.015625f;
            float inv = rsqrtf(q * 0.015625f - mu*mu + 1e-5f);
            cf0 = mk8(lnq(xv0,mu,inv,PG4(128), PG4(192)),
                      lnq(xv1,mu,inv,PG4(144), PG4(208)));
            cf1 = mk8(lnq(xv2,mu,inv,PG4(160), PG4(224)),
                      lnq(xv3,mu,inv,PG4(176), PG4(240)));
        }
        SB();

        // ---- MLP: unroll 1 + per-step fence bounds hoisting to 8 frags ----
        f32x4 fa0 = zf, fa1 = zf, fa2 = zf, fa3 = zf;
        #pragma unroll 1
        for (int m2 = 0; m2 < 8; ++m2) {
            int t0 = 2*m2, t1 = 2*m2 + 1;
            f32x4 aa = MFMA(WFL(32+t0*2+0), cf0, zf);
            aa       = MFMA(WFL(32+t0*2+1), cf1, aa);
            uint2 fr0 = relupack(aa, PG4(384 + 16*t0));
            f32x4 ac = MFMA(WFL(32+t1*2+0), cf0, zf);
            ac       = MFMA(WFL(32+t1*2+1), cf1, ac);
            uint2 fr1 = relupack(ac, PG4(384 + 16*t1));
            bf16x8 ffr = mk8(fr0, fr1);
            fa0 = MFMA(WFL(64 + 0*8 + m2), ffr, fa0);
            fa1 = MFMA(WFL(64 + 1*8 + m2), ffr, fa1);
            fa2 = MFMA(WFL(64 + 2*8 + m2), ffr, fa2);
            fa3 = MFMA(WFL(64 + 3*8 + m2), ffr, fa3);
            SB();
        }

        // ---- +b2, residual 2, store ----
        #define STORE(NT, XV, FA) { \
            f32x4 bv = PG4(320 + 16*(NT)); \
            f32x4 o; \
            o[0]=XV[0]+FA[0]+bv[0]; o[1]=XV[1]+FA[1]+bv[1]; \
            o[2]=XV[2]+FA[2]+bv[2]; o[3]=XV[3]+FA[3]+bv[3]; \
            *(f32x4*)(obp + xoff + 16*(NT)) = o; }
        STORE(0, xv0, fa0); STORE(1, xv1, fa1);
        STORE(2, xv2, fa2); STORE(3, xv3, fa3);
        #undef STORE
        #undef ACC4
    }
    #undef WFL
    #undef PG4
}

extern "C" void kernel_launch(void* const* d_in, const int* in_sizes, int n_in,
                              void* d_out, int out_size, void* d_ws, size_t ws_size,
                              hipStream_t stream) {
    const float* x   = (const float*)d_in[0];
    const float* Wq  = (const float*)d_in[1];
    const float* Wk  = (const float*)d_in[2];
    const float* Wv  = (const float*)d_in[3];
    const float* Wp  = (const float*)d_in[4];
    const float* bp  = (const float*)d_in[5];
    const float* W1  = (const float*)d_in[6];
    const float* b1  = (const float*)d_in[7];
    const float* W2  = (const float*)d_in[8];
    const float* b2  = (const float*)d_in[9];
    const float* g1  = (const float*)d_in[10];
    const float* be1 = (const float*)d_in[11];
    const float* g2  = (const float*)d_in[12];
    const float* be2 = (const float*)d_in[13];
    int nPairs = in_sizes[0] / 1024;   // (B*T*C) / (2*8*64) = 32768
    fused_block<<<dim3(256), dim3(512), 0, stream>>>(
        x, Wq, Wk, Wv, Wp, bp, W1, b1, W2, b2, g1, be1, g2, be2,
        (float*)d_out, nPairs);
}

// Round 16
// 117.398 us; speedup vs baseline: 9.6951x; 1.0329x over previous
//
#include <hip/hip_runtime.h>
#include <hip/hip_bf16.h>
#include <stdint.h>

typedef __attribute__((ext_vector_type(8))) short bf16x8;
typedef __attribute__((ext_vector_type(4))) float f32x4;

// ALL-REGISTER transformer block, ONE pair (16 rows) per wave, scheduler
// fences, 768-thread blocks.
//
// REGALLOC MODEL (rounds 9-15, now 4-point-confirmed): the backend budgets
// VGPRs for TWO workgroups/CU regardless of LDS: cap = 65536/threads
// (512->128, 768->85, 1024->64). Our 100 KB LDS admits only 1 WG/CU, so
// threads/block directly trades VGPR cap vs waves/SIMD:
//   512 thr: cap 128, 2 waves/SIMD (round 15: 121us, VALU 55%, occ 20%)
//   768 thr: cap  85, 3 waves/SIMD  <- this round; demand cut to ~72 by
//                                       dropping the x-prefetch (-16 regs)
// Scheduler fences (sched_barrier(0) per phase + unroll-1 MLP) keep the
// pre-RA scheduler from hoisting ds_read results across phases (round 14's
// 1.4 GB spill-reload). Both remain essential.
//
// Transposed-chaining math identical to rounds 9-15 (PASSED, absmax 0.031):
// k = 8*fg+j <-> logical c = 16*(2m+u)+4*fg+(j&3), u=j>>2, applied to both
// register tiles and the weight pre-pack. x ownership: lane(fr,fg) owns row
// fr, cols 16*nt+4*fg+r. Each f32x4 global access covers 16 full 64-B
// sectors -> fully coalesced.
//
// LDS map (read-only after preload; no in-loop stores, no barriers):
//   [0, 98304)  96 weight fragments, bf16, frag f at byte f*1024 + lane*16:
//     f 0..23: QKV (f = sel*8 + hd*2 + m)   f 24..31: Wp^T
//     f 32..63: W1^T (f = 32 + t*2 + m)     f 64..95: W2^T (f = 64 + nt*8 + m)
//   [98304, 100864) params f32: g1@0 be1@64 g2@128 be2@192 bp@256 b2@320 b1@384

static __device__ __forceinline__ unsigned short f2bf(float f) {
    union { __hip_bfloat16 h; unsigned short u; } cv;
    cv.h = __float2bfloat16(f);
    return cv.u;
}
static __device__ __forceinline__ unsigned int f2bf2(float a, float b) {
    return (unsigned int)f2bf(a) | ((unsigned int)f2bf(b) << 16);
}
static __device__ __forceinline__ bf16x8 mk8(uint2 a, uint2 b) {
    union { uint4 u; bf16x8 v; } c;
    c.u = make_uint4(a.x, a.y, b.x, b.y);
    return c.v;
}
static __device__ __forceinline__ uint2 packbf(f32x4 a) {
    return make_uint2(f2bf2(a[0], a[1]), f2bf2(a[2], a[3]));
}
static __device__ __forceinline__ uint2 lnq(f32x4 x, float mu, float inv, f32x4 g, f32x4 b) {
    return make_uint2(f2bf2((x[0]-mu)*inv*g[0]+b[0], (x[1]-mu)*inv*g[1]+b[1]),
                      f2bf2((x[2]-mu)*inv*g[2]+b[2], (x[3]-mu)*inv*g[3]+b[3]));
}
static __device__ __forceinline__ uint2 relupack(f32x4 a, f32x4 b) {
    return make_uint2(f2bf2(fmaxf(a[0]+b[0],0.f), fmaxf(a[1]+b[1],0.f)),
                      f2bf2(fmaxf(a[2]+b[2],0.f), fmaxf(a[3]+b[3],0.f)));
}

#define MFMA(A,B,C) __builtin_amdgcn_mfma_f32_16x16x32_bf16((A),(B),(C),0,0,0)
#define SB() __builtin_amdgcn_sched_barrier(0)

// QK^T scores -> masked exp (no max-sub: |s|<~2 by construction) -> PV.
// Lane holds S[tq=fr][tk=4fg+r]; rowsum across fg via xor 16,32.
static __device__ __forceinline__ uint2 attn_tail(f32x4 sa, uint2 vw, int fr, int fg) {
    const f32x4 zf = {0.f,0.f,0.f,0.f};
    const uint2 z2 = make_uint2(0u,0u);
    int tk0 = 4*fg, frq = fr & 7;
    bool v8 = ((fr ^ tk0) & 8) == 0;
    float p0 = (v8 && (((tk0+0)&7) <= frq)) ? __expf(sa[0]*0.125f) : 0.f;
    float p1 = (v8 && (((tk0+1)&7) <= frq)) ? __expf(sa[1]*0.125f) : 0.f;
    float p2 = (v8 && (((tk0+2)&7) <= frq)) ? __expf(sa[2]*0.125f) : 0.f;
    float p3 = (v8 && (((tk0+3)&7) <= frq)) ? __expf(sa[3]*0.125f) : 0.f;
    float rsum = p0 + p1 + p2 + p3;
    rsum += __shfl_xor(rsum, 16, 64);
    rsum += __shfl_xor(rsum, 32, 64);
    float pinv = __builtin_amdgcn_rcpf(rsum);
    uint2 pb = make_uint2(f2bf2(p0,p1), f2bf2(p2,p3));
    f32x4 oa = MFMA(mk8(vw, z2), mk8(pb, z2), zf);
    return make_uint2(f2bf2(oa[0]*pinv, oa[1]*pinv), f2bf2(oa[2]*pinv, oa[3]*pinv));
}

// One attention head for one 16-row tile; weight frags passed by value.
static __device__ __forceinline__ uint2 attn_head(
    bf16x8 wq0, bf16x8 wq1, bf16x8 wk0, bf16x8 wk1, bf16x8 wv0, bf16x8 wv1,
    bf16x8 h0, bf16x8 h1, int fr, int fg)
{
    const f32x4 zf = {0.f,0.f,0.f,0.f};
    const uint2 z2 = make_uint2(0u,0u);
    f32x4 qa = MFMA(wq0, h0, zf); qa = MFMA(wq1, h1, qa);
    f32x4 ka = MFMA(wk0, h0, zf); ka = MFMA(wk1, h1, ka);
    f32x4 va = MFMA(h0, wv0, zf); va = MFMA(h1, wv1, va);
    uint2 qw = packbf(qa), kw = packbf(ka), vw = packbf(va);
    f32x4 sa = MFMA(mk8(kw, z2), mk8(qw, z2), zf);
    return attn_tail(sa, vw, fr, fg);
}

__global__ __launch_bounds__(768, 1)
void fused_block(const float* __restrict__ xg,
                 const float* __restrict__ Wq, const float* __restrict__ Wk,
                 const float* __restrict__ Wv, const float* __restrict__ Wp,
                 const float* __restrict__ bp, const float* __restrict__ W1,
                 const float* __restrict__ b1, const float* __restrict__ W2,
                 const float* __restrict__ b2, const float* __restrict__ g1,
                 const float* __restrict__ be1, const float* __restrict__ g2,
                 const float* __restrict__ be2, float* __restrict__ out,
                 int nPairsTotal)
{
    __shared__ __align__(16) unsigned char LDS[100864];

    const int tid  = threadIdx.x;
    const int lane = tid & 63;
    const int wid  = tid >> 6;        // 0..11
    const int fr   = lane & 15;
    const int fg   = lane >> 4;

    // ---------------- weight pre-pack (identical math to round 9) -----------
    {
        unsigned short* lw = (unsigned short*)LDS;
        #pragma unroll 1
        for (int e = tid; e < 49152; e += 768) {
            int j = e & 7, ln = (e >> 3) & 63, f = e >> 9;
            int fr_ = ln & 15, fg_ = ln >> 4;
            int u = j >> 2, r_ = j & 3;
            float src;
            if (f < 24) {                 // QKV: f = sel*8 + hd*2 + m
                int sel = f >> 3, hd = (f >> 1) & 3, m = f & 1;
                int c = 16*(2*m + u) + 4*fg_ + r_;
                const float* W = (sel == 0) ? Wq : ((sel == 1) ? Wk : Wv);
                src = W[hd*1024 + c*16 + fr_];
            } else if (f < 32) {          // Wp^T
                int t = f - 24, nt = t >> 1, m = t & 1;
                int d = 16*(2*m + u) + 4*fg_ + r_;
                src = Wp[d*64 + 16*nt + fr_];
            } else if (f < 64) {          // W1^T
                int t = f - 32, tt = t >> 1, m = t & 1;
                int c = 16*(2*m + u) + 4*fg_ + r_;
                src = W1[c*256 + 16*tt + fr_];
            } else {                      // W2^T
                int t = f - 64, nt = t >> 3, m = t & 7;
                int n1 = 16*(2*m + u) + 4*fg_ + r_;
                src = W2[n1*64 + 16*nt + fr_];
            }
            lw[e] = f2bf(src);
        }
    }
    if (tid < 640) {   // params
        float v;
        if      (tid < 64)  v = g1[tid];
        else if (tid < 128) v = be1[tid - 64];
        else if (tid < 192) v = g2[tid - 128];
        else if (tid < 256) v = be2[tid - 192];
        else if (tid < 320) v = bp[tid - 256];
        else if (tid < 384) v = b2[tid - 320];
        else                v = b1[tid - 384];
        ((float*)(LDS + 98304))[tid] = v;
    }
    __syncthreads();

    const float* PG = (const float*)(LDS + 98304);
    #define WFL(F) (*(const bf16x8*)(LDS + ((F) << 10) + (lane << 4)))
    #define PG4(I) (*(const f32x4*)(PG + (I) + 4*fg))

    const int pipe = blockIdx.x * 12 + wid;   // 256*12 = 3072 pipes
    const f32x4 zf = {0.f, 0.f, 0.f, 0.f};
    const int xoff = fr*64 + 4*fg;

    #pragma unroll 1
    for (int gp = pipe; gp < nPairsTotal; gp += 3072) {
        const float* xb = xg + (size_t)gp * 1024;
        float*      obp = out + (size_t)gp * 1024;

        // direct x load (no prefetch: -16 regs to fit the 85-VGPR cap;
        // 3 waves/SIMD hide the latency instead)
        f32x4 xv0 = *(const f32x4*)(xb + xoff);
        f32x4 xv1 = *(const f32x4*)(xb + xoff + 16);
        f32x4 xv2 = *(const f32x4*)(xb + xoff + 32);
        f32x4 xv3 = *(const f32x4*)(xb + xoff + 48);
        SB();

        #define ACC4(S,SS,V) { S += V[0]+V[1]+V[2]+V[3]; \
                               SS += V[0]*V[0]+V[1]*V[1]+V[2]*V[2]+V[3]*V[3]; }

        // ---- LN1 (row = fr; reduce across fg via xor 16,32) -> h frags ----
        bf16x8 hf0, hf1;
        {
            float s = 0.f, q = 0.f;
            ACC4(s,q,xv0); ACC4(s,q,xv1); ACC4(s,q,xv2); ACC4(s,q,xv3);
            s += __shfl_xor(s,16,64); q += __shfl_xor(q,16,64);
            s += __shfl_xor(s,32,64); q += __shfl_xor(q,32,64);
            float mu  = s * 0.015625f;
            float inv = rsqrtf(q * 0.015625f - mu*mu + 1e-5f);
            hf0 = mk8(lnq(xv0,mu,inv,PG4(0),  PG4(64)),
                      lnq(xv1,mu,inv,PG4(16), PG4(80)));
            hf1 = mk8(lnq(xv2,mu,inv,PG4(32), PG4(96)),
                      lnq(xv3,mu,inv,PG4(48), PG4(112)));
        }
        SB();

        // ---- attention: 4 heads, fenced so loads stay within their phase ----
        uint2 o0, o1, o2, o3;
        o0 = attn_head(WFL(0), WFL(1), WFL(8),  WFL(9),  WFL(16), WFL(17), hf0, hf1, fr, fg);
        SB();
        o1 = attn_head(WFL(2), WFL(3), WFL(10), WFL(11), WFL(18), WFL(19), hf0, hf1, fr, fg);
        SB();
        o2 = attn_head(WFL(4), WFL(5), WFL(12), WFL(13), WFL(20), WFL(21), hf0, hf1, fr, fg);
        SB();
        o3 = attn_head(WFL(6), WFL(7), WFL(14), WFL(15), WFL(22), WFL(23), hf0, hf1, fr, fg);
        SB();

        // ---- proj: sa^T = Wp^T O^T (+bp), residual into xv ----
        {
            bf16x8 olo = mk8(o0, o1), ohi = mk8(o2, o3);
            #define PROJ(NT, XV) { \
                f32x4 pa = MFMA(WFL(24+(NT)*2+0), olo, zf); \
                pa       = MFMA(WFL(24+(NT)*2+1), ohi, pa); \
                f32x4 bv = PG4(256 + 16*(NT)); \
                XV[0]+=pa[0]+bv[0]; XV[1]+=pa[1]+bv[1]; \
                XV[2]+=pa[2]+bv[2]; XV[3]+=pa[3]+bv[3]; }
            PROJ(0, xv0); PROJ(1, xv1); PROJ(2, xv2); PROJ(3, xv3);
            #undef PROJ
        }
        SB();

        // ---- LN2 -> h2 frags ----
        bf16x8 cf0, cf1;
        {
            float s = 0.f, q = 0.f;
            ACC4(s,q,xv0); ACC4(s,q,xv1); ACC4(s,q,xv2); ACC4(s,q,xv3);
            s += __shfl_xor(s,16,64); q += __shfl_xor(q,16,64);
            s += __shfl_xor(s,32,64); q += __shfl_xor(q,32,64);
            float mu  = s * 0.015625f;
            float inv = rsqrtf(q * 0.015625f - mu*mu + 1e-5f);
            cf0 = mk8(lnq(xv0,mu,inv,PG4(128), PG4(192)),
                      lnq(xv1,mu,inv,PG4(144), PG4(208)));
            cf1 = mk8(lnq(xv2,mu,inv,PG4(160), PG4(224)),
                      lnq(xv3,mu,inv,PG4(176), PG4(240)));
        }
        SB();

        // ---- MLP: unroll 1 + per-step fence bounds hoisting to 8 frags ----
        f32x4 fa0 = zf, fa1 = zf, fa2 = zf, fa3 = zf;
        #pragma unroll 1
        for (int m2 = 0; m2 < 8; ++m2) {
            int t0 = 2*m2, t1 = 2*m2 + 1;
            f32x4 aa = MFMA(WFL(32+t0*2+0), cf0, zf);
            aa       = MFMA(WFL(32+t0*2+1), cf1, aa);
            uint2 fr0 = relupack(aa, PG4(384 + 16*t0));
            f32x4 ac = MFMA(WFL(32+t1*2+0), cf0, zf);
            ac       = MFMA(WFL(32+t1*2+1), cf1, ac);
            uint2 fr1 = relupack(ac, PG4(384 + 16*t1));
            bf16x8 ffr = mk8(fr0, fr1);
            fa0 = MFMA(WFL(64 + 0*8 + m2), ffr, fa0);
            fa1 = MFMA(WFL(64 + 1*8 + m2), ffr, fa1);
            fa2 = MFMA(WFL(64 + 2*8 + m2), ffr, fa2);
            fa3 = MFMA(WFL(64 + 3*8 + m2), ffr, fa3);
            SB();
        }

        // ---- +b2, residual 2, store ----
        #define STORE(NT, XV, FA) { \
            f32x4 bv = PG4(320 + 16*(NT)); \
            f32x4 o; \
            o[0]=XV[0]+FA[0]+bv[0]; o[1]=XV[1]+FA[1]+bv[1]; \
            o[2]=XV[2]+FA[2]+bv[2]; o[3]=XV[3]+FA[3]+bv[3]; \
            *(f32x4*)(obp + xoff + 16*(NT)) = o; }
        STORE(0, xv0, fa0); STORE(1, xv1, fa1);
        STORE(2, xv2, fa2); STORE(3, xv3, fa3);
        #undef STORE
        #undef ACC4
    }
    #undef WFL
    #undef PG4
}

extern "C" void kernel_launch(void* const* d_in, const int* in_sizes, int n_in,
                              void* d_out, int out_size, void* d_ws, size_t ws_size,
                              hipStream_t stream) {
    const float* x   = (const float*)d_in[0];
    const float* Wq  = (const float*)d_in[1];
    const float* Wk  = (const float*)d_in[2];
    const float* Wv  = (const float*)d_in[3];
    const float* Wp  = (const float*)d_in[4];
    const float* bp  = (const float*)d_in[5];
    const float* W1  = (const float*)d_in[6];
    const float* b1  = (const float*)d_in[7];
    const float* W2  = (const float*)d_in[8];
    const float* b2  = (const float*)d_in[9];
    const float* g1  = (const float*)d_in[10];
    const float* be1 = (const float*)d_in[11];
    const float* g2  = (const float*)d_in[12];
    const float* be2 = (const float*)d_in[13];
    int nPairs = in_sizes[0] / 1024;   // (B*T*C) / (2*8*64) = 32768
    fused_block<<<dim3(256), dim3(768), 0, stream>>>(
        x, Wq, Wk, Wv, Wp, bp, W1, b1, W2, b2, g1, be1, g2, be2,
        (float*)d_out, nPairs);
}